// Round 2
// baseline (1432.297 us; speedup 1.0000x reference)
//
#include <hip/hip_runtime.h>
#include <hip/hip_bf16.h>

// Problem constants
#define NPOLY (16 * 1024)   // B*N
#define NPTS  21
#define P     20            // NPTS-1 rows per polyline
#define SS_SZ 2736          // h1[0,2560) | feat[2560,2680) | pts[2688,2730)

// ---------------------------------------------------------------------------
// Kernel 0: normalize mask (handles numpy-bool bytes OR int32) into d_ws,
// and write output 2 (~mask as float). Single block, deterministic.
// ---------------------------------------------------------------------------
__global__ __launch_bounds__(256) void norm_mask(
    const unsigned char* __restrict__ mraw,
    unsigned char* __restrict__ mout, float* __restrict__ out2)
{
    __shared__ int s_nz;
    if (threadIdx.x == 0) s_nz = 0;
    __syncthreads();
    int local = 0;
    for (int i = threadIdx.x; i < NPOLY; i += 256)
        if ((i & 3) != 0) local |= mraw[i];
    if (local) atomicOr(&s_nz, 1);
    __syncthreads();
    const bool isByte = (s_nz != 0);      // int32 0/1 LE => bytes at i%4!=0 all zero
    const int* mi = (const int*)mraw;
    for (int i = threadIdx.x; i < NPOLY; i += 256) {
        const unsigned char v = isByte ? (mraw[i] != 0) : (mi[i] != 0);
        mout[i] = v;
        out2[i] = v ? 0.0f : 1.0f;
    }
}

// ---------------------------------------------------------------------------
// Kernel A: per-polyline MLP encoder (2 polylines per block, 256 threads).
// Thread t: half = t>>7 selects polyline, lc = t&127; owns columns {lc, lc+128}.
// LDS 63.4 KiB: sH = h then h2a in place (20x256/poly), sS = h1|feat|pts, sPool.
// ---------------------------------------------------------------------------
__global__ __launch_bounds__(256) void enc_main(
    const float* __restrict__ tgt, const int* __restrict__ label,
    const unsigned char* __restrict__ mask,
    const float* __restrict__ W1, const float* __restrict__ b1,
    const float* __restrict__ g1, const float* __restrict__ be1,
    const float* __restrict__ m1, const float* __restrict__ v1,
    const float* __restrict__ W2, const float* __restrict__ b2,
    const float* __restrict__ W3, const float* __restrict__ b3,
    const float* __restrict__ g2, const float* __restrict__ be2,
    const float* __restrict__ m2, const float* __restrict__ v2,
    const float* __restrict__ W4, const float* __restrict__ b4,
    const float* __restrict__ temb, float* __restrict__ out0)
{
    __shared__ __align__(16) float sH[2][P * 256];   // 40 KB: h, then h2a in place
    __shared__ __align__(16) float sS[2][SS_SZ];     // 21.4 KB
    __shared__ __align__(16) float sPool[2][256];    // 2 KB

    const int tid  = threadIdx.x;
    const int half = tid >> 7;
    const int lc   = tid & 127;
    const int poly = blockIdx.x * 2 + half;
    const bool act = (mask[poly] != 0);

    // --- load 21 points (42 floats) ---
    if (act && lc < 42) sS[half][2688 + lc] = tgt[poly * 42 + lc];
    __syncthreads();

    // --- feat = [rel(2), pv(2), orient(2)] per point p<20 ---
    if (act && lc < P) {
        const float* pts = &sS[half][2688];
        const float px = pts[lc * 2 + 0], py = pts[lc * 2 + 1];
        const float qx = pts[lc * 2 + 2], qy = pts[lc * 2 + 3];
        const float cx = pts[20],         cy = pts[21];       // center = point 10
        const float vx = qx - px, vy = qy - py;
        // reference: vnorm = ||pv|| + mask(=1 for active) + 1e-6
        const float inv = 1.0f / (sqrtf(vx * vx + vy * vy) + 1.0f + 1e-6f);
        float* f = &sS[half][2560 + lc * 6];
        f[0] = px - cx; f[1] = py - cy; f[2] = vx; f[3] = vy; f[4] = vx * inv; f[5] = vy * inv;
    }
    __syncthreads();

    // --- S2: h1 = relu(bn1(feat @ W1 + b1)), 20x128; thread owns col lc ---
    if (act) {
        float w[6];
        #pragma unroll
        for (int k = 0; k < 6; k++) w[k] = W1[k * 128 + lc];
        const float bb  = b1[lc];
        const float sc  = rsqrtf(v1[lc] + 1e-5f) * g1[lc];
        const float off = be1[lc] - m1[lc] * sc;
        #pragma unroll
        for (int p = 0; p < P; p++) {
            const float* f = &sS[half][2560 + p * 6];
            float a = bb;
            #pragma unroll
            for (int k = 0; k < 6; k++) a = fmaf(f[k], w[k], a);
            a = fmaf(a, sc, off);
            sS[half][p * 128 + lc] = fmaxf(a, 0.0f);
        }
    }
    __syncthreads();

    const int c0 = lc, c1 = lc + 128;

    // --- S3: h = h1 @ W2 + b2 (masked);  pooled = max_p h ---
    if (act) {
        float acc0[P], acc1[P];
        #pragma unroll
        for (int p = 0; p < P; p++) { acc0[p] = 0.f; acc1[p] = 0.f; }
        for (int k4 = 0; k4 < 32; k4++) {
            float wa[4], wb[4];
            #pragma unroll
            for (int q = 0; q < 4; q++) {
                wa[q] = W2[(k4 * 4 + q) * 256 + c0];
                wb[q] = W2[(k4 * 4 + q) * 256 + c1];
            }
            #pragma unroll
            for (int p = 0; p < P; p++) {
                const float4 h = *(const float4*)&sS[half][p * 128 + k4 * 4];
                acc0[p] = fmaf(h.x, wa[0], fmaf(h.y, wa[1], fmaf(h.z, wa[2], fmaf(h.w, wa[3], acc0[p]))));
                acc1[p] = fmaf(h.x, wb[0], fmaf(h.y, wb[1], fmaf(h.z, wb[2], fmaf(h.w, wb[3], acc1[p]))));
            }
        }
        const float bb0 = b2[c0], bb1 = b2[c1];
        float mx0 = -1e30f, mx1 = -1e30f;
        #pragma unroll
        for (int p = 0; p < P; p++) {
            const float v0 = acc0[p] + bb0, v1_ = acc1[p] + bb1;
            sH[half][p * 256 + c0] = v0;
            sH[half][p * 256 + c1] = v1_;
            mx0 = fmaxf(mx0, v0); mx1 = fmaxf(mx1, v1_);
        }
        sPool[half][c0] = mx0; sPool[half][c1] = mx1;
    }
    __syncthreads();

    // --- S4: h2a = relu(bn2(cat @ W3 + b3)); cat = [h | pooled].
    // pooled part is row-invariant (once per column). h2a overwrites sH in
    // place: read-phase into regs, barrier, write-phase, barrier.
    {
        float acc0[P], acc1[P];
        float bb0 = 0.f, bb1 = 0.f, sc0 = 0.f, off0 = 0.f, sc1 = 0.f, off1 = 0.f;
        if (act) {
            #pragma unroll
            for (int p = 0; p < P; p++) { acc0[p] = 0.f; acc1[p] = 0.f; }
            for (int k4 = 0; k4 < 64; k4++) {
                float wa[4], wb[4];
                #pragma unroll
                for (int q = 0; q < 4; q++) {
                    wa[q] = W3[(k4 * 4 + q) * 256 + c0];
                    wb[q] = W3[(k4 * 4 + q) * 256 + c1];
                }
                #pragma unroll
                for (int p = 0; p < P; p++) {
                    const float4 h = *(const float4*)&sH[half][p * 256 + k4 * 4];
                    acc0[p] = fmaf(h.x, wa[0], fmaf(h.y, wa[1], fmaf(h.z, wa[2], fmaf(h.w, wa[3], acc0[p]))));
                    acc1[p] = fmaf(h.x, wb[0], fmaf(h.y, wb[1], fmaf(h.z, wb[2], fmaf(h.w, wb[3], acc1[p]))));
                }
            }
            float ap0 = 0.f, ap1 = 0.f;
            for (int k4 = 0; k4 < 64; k4++) {
                const float4 pl = *(const float4*)&sPool[half][k4 * 4];
                float wa[4], wb[4];
                #pragma unroll
                for (int q = 0; q < 4; q++) {
                    wa[q] = W3[(256 + k4 * 4 + q) * 256 + c0];
                    wb[q] = W3[(256 + k4 * 4 + q) * 256 + c1];
                }
                ap0 = fmaf(pl.x, wa[0], fmaf(pl.y, wa[1], fmaf(pl.z, wa[2], fmaf(pl.w, wa[3], ap0))));
                ap1 = fmaf(pl.x, wb[0], fmaf(pl.y, wb[1], fmaf(pl.z, wb[2], fmaf(pl.w, wb[3], ap1))));
            }
            sc0  = rsqrtf(v2[c0] + 1e-5f) * g2[c0];
            off0 = be2[c0] - m2[c0] * sc0;
            sc1  = rsqrtf(v2[c1] + 1e-5f) * g2[c1];
            off1 = be2[c1] - m2[c1] * sc1;
            bb0 = b3[c0] + ap0; bb1 = b3[c1] + ap1;
        }
        __syncthreads();   // all reads of sH (h) complete before overwrite
        if (act) {
            #pragma unroll
            for (int p = 0; p < P; p++) {
                const float v0  = fmaf(acc0[p] + bb0, sc0, off0);
                const float v1_ = fmaf(acc1[p] + bb1, sc1, off1);
                sH[half][p * 256 + c0] = fmaxf(v0, 0.f);
                sH[half][p * 256 + c1] = fmaxf(v1_, 0.f);
            }
        }
    }
    __syncthreads();

    // --- S5: x_poly = max_p(h2a @ W4 + b4) + type_emb[label]; masked write ---
    if (act) {
        float acc0[P], acc1[P];
        #pragma unroll
        for (int p = 0; p < P; p++) { acc0[p] = 0.f; acc1[p] = 0.f; }
        for (int k4 = 0; k4 < 64; k4++) {
            float wa[4], wb[4];
            #pragma unroll
            for (int q = 0; q < 4; q++) {
                wa[q] = W4[(k4 * 4 + q) * 256 + c0];
                wb[q] = W4[(k4 * 4 + q) * 256 + c1];
            }
            #pragma unroll
            for (int p = 0; p < P; p++) {
                const float4 h = *(const float4*)&sH[half][p * 256 + k4 * 4];
                acc0[p] = fmaf(h.x, wa[0], fmaf(h.y, wa[1], fmaf(h.z, wa[2], fmaf(h.w, wa[3], acc0[p]))));
                acc1[p] = fmaf(h.x, wb[0], fmaf(h.y, wb[1], fmaf(h.z, wb[2], fmaf(h.w, wb[3], acc1[p]))));
            }
        }
        const float bb0 = b4[c0], bb1 = b4[c1];
        float mx0 = -1e30f, mx1 = -1e30f;
        #pragma unroll
        for (int p = 0; p < P; p++) {
            mx0 = fmaxf(mx0, acc0[p] + bb0);
            mx1 = fmaxf(mx1, acc1[p] + bb1);
        }
        const int lb = label[poly];
        out0[(size_t)poly * 256 + c0] = mx0 + temb[lb * 256 + c0];
        out0[(size_t)poly * 256 + c1] = mx1 + temb[lb * 256 + c1];
    } else {
        out0[(size_t)poly * 256 + c0] = 0.f;
        out0[(size_t)poly * 256 + c1] = 0.f;
    }
}

// ---------------------------------------------------------------------------
// Kernel B: sine positional embedding MLP, 16 polylines per block (48.3 KB LDS).
// pe = relu(sine @ Wp1 + bp1) @ Wp2 + bp2, masked.
// ---------------------------------------------------------------------------
#define RPE 16
__global__ __launch_bounds__(256) void enc_pe(
    const float* __restrict__ tgt, const unsigned char* __restrict__ mask,
    const float* __restrict__ Wp1, const float* __restrict__ bp1,
    const float* __restrict__ Wp2, const float* __restrict__ bp2,
    const float* __restrict__ pcr, float* __restrict__ out1)
{
    __shared__ float sPos[RPE][2];
    __shared__ float sMk[RPE];
    __shared__ __align__(16) float sSine[RPE][256];   // 16 KB
    __shared__ __align__(16) float sPh[RPE][512];     // 32 KB

    const int tid  = threadIdx.x;
    const int base = blockIdx.x * RPE;

    if (tid < 2 * RPE) {
        const int r = tid >> 1, d = tid & 1;
        const float c  = tgt[(size_t)(base + r) * 42 + 20 + d];  // center point 10
        const float lo = pcr[d], hi = pcr[3 + d];
        sPos[r][d] = (c - lo) / (hi - lo);
    }
    if (tid < RPE) sMk[tid] = (mask[base + tid] != 0) ? 1.0f : 0.0f;
    __syncthreads();

    // sine embedding: out = concat([ey, ex]); c<128 -> y axis, c>=128 -> x axis.
    // within 128: pairs (sin, cos) at freq 2*pi*10000^(-i/64), i = (c&127)>>1.
    {
        const int axis = (tid < 128) ? 1 : 0;
        const int j7 = tid & 127;
        const int i  = j7 >> 1;
        const float freq = exp2f(-(float)i * (13.287712379549449f / 64.0f)) * 6.283185307179586f;
        const bool isc = (j7 & 1);
        #pragma unroll
        for (int r = 0; r < RPE; r++) {
            const float v = sPos[r][axis] * freq;
            sSine[r][tid] = isc ? cosf(v) : sinf(v);
        }
    }
    __syncthreads();

    // phase 2: ph = relu(sine @ Wp1 + bp1); thread owns cols {tid, tid+256}
    {
        float acc0[RPE], acc1[RPE];
        #pragma unroll
        for (int r = 0; r < RPE; r++) { acc0[r] = 0.f; acc1[r] = 0.f; }
        const int c0 = tid, c1 = tid + 256;
        for (int k4 = 0; k4 < 64; k4++) {
            float wa[4], wb[4];
            #pragma unroll
            for (int q = 0; q < 4; q++) {
                wa[q] = Wp1[(k4 * 4 + q) * 512 + c0];
                wb[q] = Wp1[(k4 * 4 + q) * 512 + c1];
            }
            #pragma unroll
            for (int r = 0; r < RPE; r++) {
                const float4 s = *(const float4*)&sSine[r][k4 * 4];
                acc0[r] = fmaf(s.x, wa[0], fmaf(s.y, wa[1], fmaf(s.z, wa[2], fmaf(s.w, wa[3], acc0[r]))));
                acc1[r] = fmaf(s.x, wb[0], fmaf(s.y, wb[1], fmaf(s.z, wb[2], fmaf(s.w, wb[3], acc1[r]))));
            }
        }
        const float ba = bp1[c0], bb = bp1[c1];
        #pragma unroll
        for (int r = 0; r < RPE; r++) {
            sPh[r][c0] = fmaxf(acc0[r] + ba, 0.f);
            sPh[r][c1] = fmaxf(acc1[r] + bb, 0.f);
        }
    }
    __syncthreads();

    // phase 3: pe = ph @ Wp2 + bp2; thread owns col tid
    {
        float acc2[RPE];
        #pragma unroll
        for (int r = 0; r < RPE; r++) acc2[r] = 0.f;
        for (int k4 = 0; k4 < 128; k4++) {
            float w[4];
            #pragma unroll
            for (int q = 0; q < 4; q++) w[q] = Wp2[(k4 * 4 + q) * 256 + tid];
            #pragma unroll
            for (int r = 0; r < RPE; r++) {
                const float4 p = *(const float4*)&sPh[r][k4 * 4];
                acc2[r] = fmaf(p.x, w[0], fmaf(p.y, w[1], fmaf(p.z, w[2], fmaf(p.w, w[3], acc2[r]))));
            }
        }
        const float bo = bp2[tid];
        #pragma unroll
        for (int r = 0; r < RPE; r++) {
            out1[(size_t)(base + r) * 256 + tid] = (sMk[r] != 0.f) ? (acc2[r] + bo) : 0.f;
        }
    }
}

extern "C" void kernel_launch(void* const* d_in, const int* in_sizes, int n_in,
                              void* d_out, int out_size, void* d_ws, size_t ws_size,
                              hipStream_t stream) {
    const float*         tgt   = (const float*)d_in[0];
    const int*           label = (const int*)d_in[1];
    const unsigned char* mraw  = (const unsigned char*)d_in[2];
    const float* W1  = (const float*)d_in[3];
    const float* b1  = (const float*)d_in[4];
    const float* g1  = (const float*)d_in[5];
    const float* be1 = (const float*)d_in[6];
    const float* m1  = (const float*)d_in[7];
    const float* v1  = (const float*)d_in[8];
    const float* W2  = (const float*)d_in[9];
    const float* b2  = (const float*)d_in[10];
    const float* W3  = (const float*)d_in[11];
    const float* b3  = (const float*)d_in[12];
    const float* g2  = (const float*)d_in[13];
    const float* be2 = (const float*)d_in[14];
    const float* m2  = (const float*)d_in[15];
    const float* v2  = (const float*)d_in[16];
    const float* W4  = (const float*)d_in[17];
    const float* b4  = (const float*)d_in[18];
    const float* temb = (const float*)d_in[19];
    const float* Wp1 = (const float*)d_in[20];
    const float* bp1 = (const float*)d_in[21];
    const float* Wp2 = (const float*)d_in[22];
    const float* bp2 = (const float*)d_in[23];
    const float* pcr = (const float*)d_in[24];

    float* out0 = (float*)d_out;                              // map_feats (16384,256)
    float* out1 = out0 + (size_t)NPOLY * 256;                 // x_pos     (16384,256)
    float* out2 = out1 + (size_t)NPOLY * 256;                 // ~map_mask (16384,)

    unsigned char* mask = (unsigned char*)d_ws;               // normalized byte mask

    norm_mask<<<1, 256, 0, stream>>>(mraw, mask, out2);
    enc_main<<<NPOLY / 2, 256, 0, stream>>>(tgt, label, mask,
        W1, b1, g1, be1, m1, v1, W2, b2, W3, b3, g2, be2, m2, v2, W4, b4, temb,
        out0);
    enc_pe<<<NPOLY / RPE, 256, 0, stream>>>(tgt, mask, Wp1, bp1, Wp2, bp2, pcr, out1);
}

// Round 3
// 356.150 us; speedup vs baseline: 4.0216x; 4.0216x over previous
//
#include <hip/hip_runtime.h>

// ---------------------------------------------------------------------------
// MapEncoder on MFMA (bf16 inputs, f32 accumulate).
// Block = 8 polylines = 160 packed point-columns (10 N-tiles, zero padding).
// All GEMMs transposed: D = W^T (A-operand) @ act^T (B-operand).
// Fragment convention (HW-verified m89/m91): lane&15 = M/N index,
// 8 contiguous k per lane at k-group (lane>>4)*8; D: col=lane&15,
// row=4*(lane>>4)+reg. All LDS operands stored fragment-linear
// (frag*1024 + lane*16) -> every ds_read_b128 is lane-linear, 0 conflicts.
// ---------------------------------------------------------------------------

#define NPOLY 16384
#define NPB   8              // polylines per block
#define NC    160            // point-cols per block (8*20)
#define NT    10             // N tiles

typedef float f32x4  __attribute__((ext_vector_type(4)));
typedef short bf16x8 __attribute__((ext_vector_type(8)));

__device__ __forceinline__ unsigned short f2bf(float x) {
    union { float f; unsigned u; } v; v.f = x;
    unsigned r = v.u + 0x7FFF + ((v.u >> 16) & 1);
    return (unsigned short)(r >> 16);
}
__device__ __forceinline__ float bf2f(unsigned short s) {
    union { unsigned u; float f; } v; v.u = ((unsigned)s) << 16;
    return v.f;
}
__device__ __forceinline__ unsigned pk2(float a, float b) {
    return (unsigned)f2bf(a) | ((unsigned)f2bf(b) << 16);
}

// ---- workspace layout (bytes) ----
#define WS_MASK 0          // 16384 normalized mask bytes
#define WS_W2   16384      // 64 frags   (A-style, M=256 K=128)
#define WS_W3   81920      // 256 frags  (A-style, M=256 K=512, chunked)
#define WS_W4   344064     // 128 frags  (B-style, N=256 K=256)
#define WS_WP1  475136     // 256 frags  (A-style, M=512 K=256, chunked)
#define WS_WP2  737280     // 256 frags  (B-style, N=256 K=512)
// total 999424 bytes

// ---- enc LDS layout (dynamic, bytes) ----
#define L_CAT   0          // 80 frags: h as B-operand (kt0..7, nt0..9)   81920
#define L_H1    81920      // 40 frags: h1 B-operand (kt0..3, nt0..9)     40960
#define L_RUN   81920      // (reuse) runmax bf16 [40][256]               20480
#define L_POOL  102400     // (reuse) pooled bf16 [8][256]                 4096
#define L_H2C   122880     // 20 frags: h2 chunk A-operand (mt0..9,kt0..1)20480
#define L_FEAT  122880     // (early reuse) feat f32 [160][8]              5120
#define L_W     143360     // weight slice staging, 16 frags              16384
#define L_SC    159744     // sc2 f32[256]                                 1024
#define L_OF    160768     // off2' f32[256] (b3,m2,be2 folded)            1024
#define L_TOT   161792

// ---------------------------------------------------------------------------
// mask normalization (byte-bool or int32) -> ws, plus output 2 (~mask)
// ---------------------------------------------------------------------------
__global__ __launch_bounds__(256) void norm_mask(
    const unsigned char* __restrict__ mraw,
    unsigned char* __restrict__ mout, float* __restrict__ out2)
{
    __shared__ int s_nz;
    if (threadIdx.x == 0) s_nz = 0;
    __syncthreads();
    int local = 0;
    for (int j = 0; j < 64; j++) {
        const int i = threadIdx.x * 64 + j;          // scan first 16KB
        if ((i & 3) != 0) local |= mraw[i];
    }
    if (local) atomicOr(&s_nz, 1);
    __syncthreads();
    const bool isByte = (s_nz != 0);
    const int* mi = (const int*)mraw;
    const int i = blockIdx.x * 256 + threadIdx.x;
    const unsigned char v = isByte ? (mraw[i] != 0) : (mi[i] != 0);
    mout[i] = v;
    out2[i] = v ? 0.0f : 1.0f;
}

// ---------------------------------------------------------------------------
// weight prep: f32 -> bf16, rearranged fragment-linear into ws.
// One block per fragment (512 threads = 512 bf16 elements).
// ---------------------------------------------------------------------------
__global__ __launch_bounds__(512) void prep_weights(
    const float* __restrict__ W2, const float* __restrict__ W3,
    const float* __restrict__ W4, const float* __restrict__ Wp1,
    const float* __restrict__ Wp2, unsigned short* __restrict__ ws)
{
    const int bid = blockIdx.x;
    const float* src; int mode, MT, KS, ld, fid; size_t dst;
    if      (bid < 64)  { src = W2;  mode = 0; MT = 16; KS = 0; ld = 256; fid = bid;       dst = WS_W2;  }
    else if (bid < 320) { src = W3;  mode = 1; MT = 16; KS = 4; ld = 256; fid = bid - 64;  dst = WS_W3;  }
    else if (bid < 448) { src = W4;  mode = 2; MT = 16; KS = 0; ld = 256; fid = bid - 320; dst = WS_W4;  }
    else if (bid < 704) { src = Wp1; mode = 1; MT = 32; KS = 2; ld = 512; fid = bid - 448; dst = WS_WP1; }
    else                { src = Wp2; mode = 2; MT = 16; KS = 0; ld = 256; fid = bid - 704; dst = WS_WP2; }

    int mt, kt;
    if (mode == 0) { mt = fid & 15; kt = fid >> 4; }
    else if (mode == 1) {
        const int low = fid & 15, hi = fid >> 4;
        mt = (hi / KS) * 4 + (low >> 2);
        kt = (hi % KS) * 4 + (low & 3);
    } else { // mode 2 (B-style)
        const int low = fid & 31;
        kt = (fid >> 5) * 2 + (low & 1);
        mt = ((low >> 4) & 1) * 8 + ((low >> 1) & 7);
    }
    const int t   = threadIdx.x;
    const int l15 = t & 15, e = (t >> 4) & 7, lg = (t >> 7) & 3;
    const int m = mt * 16 + l15;
    const int k = kt * 32 + lg * 8 + e;
    const float v = src[(size_t)k * ld + m];
    ws[dst / 2 + (size_t)fid * 512 + (l15 + 16 * lg) * 8 + e] = f2bf(v);
}

// ---------------------------------------------------------------------------
// main encoder: feat -> h1 -> h (pool) -> h2 -> maxpool + type_emb
// 512 threads = 8 waves, 8 polylines per block, dynamic LDS 158 KB.
// ---------------------------------------------------------------------------
__global__ __launch_bounds__(512, 2) void enc_mfma(
    const float* __restrict__ tgt, const int* __restrict__ label,
    const unsigned char* __restrict__ mask,
    const float* __restrict__ W1, const float* __restrict__ b1,
    const float* __restrict__ g1, const float* __restrict__ be1,
    const float* __restrict__ m1, const float* __restrict__ v1,
    const float* __restrict__ b2, const float* __restrict__ b3,
    const float* __restrict__ g2, const float* __restrict__ be2,
    const float* __restrict__ m2, const float* __restrict__ v2,
    const float* __restrict__ b4, const float* __restrict__ temb,
    const unsigned short* __restrict__ ws, float* __restrict__ out0)
{
    extern __shared__ char smem[];
    const int tid  = threadIdx.x;
    const int wid  = tid >> 6;
    const int lane = tid & 63;
    const int l15  = lane & 15, lg = lane >> 4;

    // ---------- P0: feat + folded bn2 params ----------
    if (tid < NC) {
        const int c = tid, poly = c / 20, p = c - poly * 20;
        const size_t gp = (size_t)(blockIdx.x * NPB + poly) * 42;
        const float px = tgt[gp + p * 2],     py = tgt[gp + p * 2 + 1];
        const float qx = tgt[gp + p * 2 + 2], qy = tgt[gp + p * 2 + 3];
        const float cx = tgt[gp + 20],        cy = tgt[gp + 21];
        const float vx = qx - px, vy = qy - py;
        const float mk = (mask[blockIdx.x * NPB + poly] != 0) ? 1.0f : 0.0f;
        const float inv = 1.0f / (sqrtf(vx * vx + vy * vy) + mk + 1e-6f);
        float* f = (float*)(smem + L_FEAT + c * 32);
        f[0] = px - cx; f[1] = py - cy; f[2] = vx; f[3] = vy;
        f[4] = vx * inv; f[5] = vy * inv; f[6] = 0.f; f[7] = 0.f;
    }
    if (tid < 256) {
        const float sc  = rsqrtf(v2[tid] + 1e-5f) * g2[tid];
        ((float*)(smem + L_SC))[tid] = sc;
        ((float*)(smem + L_OF))[tid] = (b3[tid] - m2[tid]) * sc + be2[tid];
    }
    __syncthreads();

    // ---------- P1: S2 scalar: h1 = relu(bn1(feat@W1+b1)), write B-frags ----
    {
        const int ch = tid & 127, cblk = tid >> 7;
        float w[6];
        #pragma unroll
        for (int j = 0; j < 6; j++) w[j] = W1[j * 128 + ch];
        const float sc1  = rsqrtf(v1[ch] + 1e-5f) * g1[ch];
        const float off1 = (b1[ch] - m1[ch]) * sc1 + be1[ch];
        const int kt = ch >> 5, koff = ch & 31;
        const int lane16 = 16 * (koff >> 3);
        #pragma unroll 4
        for (int i = 0; i < 40; i++) {
            const int c = i * 4 + cblk;
            const float* f = (const float*)(smem + L_FEAT + c * 32);
            float a = 0.f;
            #pragma unroll
            for (int j = 0; j < 6; j++) a = fmaf(f[j], w[j], a);
            a = fmaxf(fmaf(a, sc1, off1), 0.f);
            *(unsigned short*)(smem + L_H1 + (kt * NT + (c >> 4)) * 1024 +
                               ((c & 15) + lane16) * 16 + (koff & 7) * 2) = f2bf(a);
        }
    }
    __syncthreads();

    // per-wave GEMM roles
    const int mw = wid >> 1;            // 0..3 (S3/S4 M-split)
    const int nw = wid & 1;             // 0..1 (5 N-tiles each)
    const int mw5 = wid >> 2;           // 0..1 (S5 M-split: 5 M-tiles each)
    const int nw5 = wid & 3;            // 0..3 (S5 N-split)

    // pooled B-operand per-lane base (col -> poly), built once
    unsigned pbase[5];
    #pragma unroll
    for (int nj = 0; nj < 5; nj++) {
        const int c = (nw * 5 + nj) * 16 + l15;
        pbase[nj] = L_POOL + (unsigned)(c / 20) * 512 + lg * 16;
    }

    // ---------- P2: S3  h^T = W2^T @ h1^T  (M=256, N=160, K=128) ----------
    {
        f32x4 acc[4][5];
        #pragma unroll
        for (int a = 0; a < 4; a++)
            #pragma unroll
            for (int b = 0; b < 5; b++) acc[a][b] = (f32x4){0.f, 0.f, 0.f, 0.f};

        for (int ks = 0; ks < 4; ks++) {
            { // stage W2 slice (16 frags)
                const uint4* g = (const uint4*)((const char*)ws + WS_W2 + ks * 16384);
                uint4* l = (uint4*)(smem + L_W);
                l[tid * 2] = g[tid * 2]; l[tid * 2 + 1] = g[tid * 2 + 1];
            }
            __syncthreads();
            bf16x8 a[4];
            #pragma unroll
            for (int mi = 0; mi < 4; mi++)
                a[mi] = *(const bf16x8*)(smem + L_W + (mw * 4 + mi) * 1024 + lane * 16);
            #pragma unroll
            for (int nj = 0; nj < 5; nj++) {
                const int nt = nw * 5 + nj;
                const bf16x8 bb = *(const bf16x8*)(smem + L_H1 + (ks * NT + nt) * 1024 + lane * 16);
                #pragma unroll
                for (int mi = 0; mi < 4; mi++)
                    acc[mi][nj] = __builtin_amdgcn_mfma_f32_16x16x32_bf16(a[mi], bb, acc[mi][nj], 0, 0, 0);
            }
            __syncthreads();
        }
        // epilogue: + b2, write catT B-frags (b64 packed)
        #pragma unroll
        for (int mi = 0; mi < 4; mi++) {
            const int mt = mw * 4 + mi, chb = mt * 16 + lg * 4;
            const float4 bv = *(const float4*)(b2 + chb);
            const int kt = chb >> 5, koff = chb & 31;
            const int lane16 = l15 + 16 * (koff >> 3);
            #pragma unroll
            for (int nj = 0; nj < 5; nj++) {
                const int nt = nw * 5 + nj;
                const f32x4 v = acc[mi][nj];
                uint2 pk;
                pk.x = pk2(v[0] + bv.x, v[1] + bv.y);
                pk.y = pk2(v[2] + bv.z, v[3] + bv.w);
                *(uint2*)(smem + L_CAT + (kt * NT + nt) * 1024 + lane16 * 16 + (koff & 7) * 2) = pk;
            }
        }
    }
    __syncthreads();

    // ---------- P3: pooled[poly][ch] = max_p h ----------
    #pragma unroll
    for (int i = 0; i < 4; i++) {
        const int idx = i * 512 + tid, poly = idx >> 8, ch = idx & 255;
        const int kt = ch >> 5, hi16 = 16 * ((ch & 31) >> 3), e2 = (ch & 7) * 2;
        float mx = -3.0e38f;
        #pragma unroll 4
        for (int p = 0; p < 20; p++) {
            const int c = poly * 20 + p;
            mx = fmaxf(mx, bf2f(*(const unsigned short*)(smem + L_CAT +
                    (kt * NT + (c >> 4)) * 1024 + ((c & 15) + hi16) * 16 + e2)));
        }
        *(unsigned short*)(smem + L_POOL + (poly * 256 + ch) * 2) = f2bf(mx);
    }
    __syncthreads();

    // ---------- P4: chunk loop — S4 (K=512) fused with S5 (K=256) ----------
    f32x4 acc5[5][4];
    #pragma unroll
    for (int a = 0; a < 5; a++)
        #pragma unroll
        for (int s = 0; s < 4; s++) acc5[a][s] = (f32x4){0.f, 0.f, 0.f, 0.f};

    for (int chunk = 0; chunk < 4; chunk++) {
        f32x4 acc4[5];
        #pragma unroll
        for (int s = 0; s < 5; s++) acc4[s] = (f32x4){0.f, 0.f, 0.f, 0.f};

        // S4: h2chunk^T = W3t[chunk] @ cat^T
        for (int ks = 0; ks < 4; ks++) {
            {
                const uint4* g = (const uint4*)((const char*)ws + WS_W3 + (chunk * 4 + ks) * 16384);
                uint4* l = (uint4*)(smem + L_W);
                l[tid * 2] = g[tid * 2]; l[tid * 2 + 1] = g[tid * 2 + 1];
            }
            __syncthreads();
            #pragma unroll
            for (int ktl = 0; ktl < 4; ktl++) {
                const int ktg = ks * 4 + ktl;
                const bf16x8 a = *(const bf16x8*)(smem + L_W + (mw * 4 + ktl) * 1024 + lane * 16);
                #pragma unroll
                for (int nj = 0; nj < 5; nj++) {
                    bf16x8 bb;
                    if (ktg < 8)
                        bb = *(const bf16x8*)(smem + L_CAT + (ktg * NT + nw * 5 + nj) * 1024 + lane * 16);
                    else
                        bb = *(const bf16x8*)(smem + pbase[nj] + (ktg - 8) * 64);
                    acc4[nj] = __builtin_amdgcn_mfma_f32_16x16x32_bf16(a, bb, acc4[nj], 0, 0, 0);
                }
            }
            __syncthreads();
        }
        // epilogue: bn2(+b3)+relu -> h2chunk A-frags (b64)
        {
            const int choff = mw * 16 + lg * 4;            // 0..63 within chunk
            const int ch = chunk * 64 + choff;
            const float4 scv = *(const float4*)(smem + L_SC + ch * 4);
            const float4 ofv = *(const float4*)(smem + L_OF + ch * 4);
            const int kt2 = choff >> 5;
            const int lane16 = l15 + 16 * ((choff & 31) >> 3);
            const int sub = (lg & 1) * 8;
            #pragma unroll
            for (int nj = 0; nj < 5; nj++) {
                const int nt = nw * 5 + nj;
                const f32x4 v = acc4[nj];
                const float r0 = fmaxf(fmaf(v[0], scv.x, ofv.x), 0.f);
                const float r1 = fmaxf(fmaf(v[1], scv.y, ofv.y), 0.f);
                const float r2 = fmaxf(fmaf(v[2], scv.z, ofv.z), 0.f);
                const float r3 = fmaxf(fmaf(v[3], scv.w, ofv.w), 0.f);
                uint2 pk; pk.x = pk2(r0, r1); pk.y = pk2(r2, r3);
                *(uint2*)(smem + L_H2C + (nt * 2 + kt2) * 1024 + lane16 * 16 + sub) = pk;
            }
        }
        // S5-partial: out^T += h2chunk @ W4t[chunk]  (A = h2c rows=cols)
        for (int half = 0; half < 2; half++) {
            __syncthreads();
            {
                const uint4* g = (const uint4*)((const char*)ws + WS_W4 + (chunk * 32 + half * 16) * 1024);
                uint4* l = (uint4*)(smem + L_W);
                l[tid * 2] = g[tid * 2]; l[tid * 2 + 1] = g[tid * 2 + 1];
            }
            __syncthreads();
            #pragma unroll
            for (int ktl = 0; ktl < 2; ktl++) {
                bf16x8 a[5];
                #pragma unroll
                for (int mi = 0; mi < 5; mi++) {
                    const int mt = mw5 * 5 + mi;
                    a[mi] = *(const bf16x8*)(smem + L_H2C + (mt * 2 + ktl) * 1024 + lane * 16);
                }
                #pragma unroll
                for (int nj = 0; nj < 2; nj++) {
                    const int ntl = nw5 * 2 + nj;
                    const bf16x8 bb = *(const bf16x8*)(smem + L_W + (ntl * 2 + ktl) * 1024 + lane * 16);
                    #pragma unroll
                    for (int mi = 0; mi < 5; mi++)
                        acc5[mi][half * 2 + nj] =
                            __builtin_amdgcn_mfma_f32_16x16x32_bf16(a[mi], bb, acc5[mi][half * 2 + nj], 0, 0, 0);
                }
            }
        }
        __syncthreads();   // protect h2c/W before next chunk
    }

    // ---------- P5: per-4-row run maxes -> LDS ----------
    #pragma unroll
    for (int mi = 0; mi < 5; mi++) {
        const int run = (mw5 * 5 + mi) * 4 + lg;
        #pragma unroll
        for (int s = 0; s < 4; s++) {
            const int nt = (s >> 1) * 8 + nw5 * 2 + (s & 1);
            const int ch = nt * 16 + l15;
            const f32x4 v = acc5[mi][s];
            const float m4 = fmaxf(fmaxf(v[0], v[1]), fmaxf(v[2], v[3]));
            *(unsigned short*)(smem + L_RUN + run * 512 + ch * 2) = f2bf(m4);
        }
    }
    __syncthreads();

    // ---------- P6: final max over runs + b4 + type_emb, masked write ------
    #pragma unroll
    for (int i = 0; i < 4; i++) {
        const int idx = i * 512 + tid, poly = idx >> 8, ch = idx & 255;
        const int gpoly = blockIdx.x * NPB + poly;
        float mx = -3.0e38f;
        #pragma unroll
        for (int j = 0; j < 5; j++)
            mx = fmaxf(mx, bf2f(*(const unsigned short*)(smem + L_RUN + (poly * 5 + j) * 512 + ch * 2)));
        const float val = mx + b4[ch] + temb[label[gpoly] * 256 + ch];
        out0[(size_t)gpoly * 256 + ch] = (mask[gpoly] != 0) ? val : 0.f;
    }
}

// ---------------------------------------------------------------------------
// PE: pe = relu(sine@Wp1+bp1)@Wp2+bp2, masked. 64 rows/block, MFMA.
// ---------------------------------------------------------------------------
#define P_SINE 0
#define P_PHC  32768
#define P_W    40960

__global__ __launch_bounds__(512, 2) void pe_mfma(
    const float* __restrict__ tgt, const unsigned char* __restrict__ mask,
    const float* __restrict__ bp1, const float* __restrict__ bp2,
    const float* __restrict__ pcr, const unsigned short* __restrict__ ws,
    float* __restrict__ out1)
{
    __shared__ __align__(16) char sm[57344];
    const int tid  = threadIdx.x;
    const int wid  = tid >> 6;
    const int lane = tid & 63;
    const int l15  = lane & 15, lg = lane >> 4;
    const int base = blockIdx.x * 64;

    const float lox = pcr[0], loy = pcr[1];
    const float sx = 1.0f / (pcr[3] - pcr[0]), sy = 1.0f / (pcr[4] - pcr[1]);

    // sine embedding -> B-frags
    #pragma unroll
    for (int i = 0; i < 4; i++) {
        const int slot = i * 512 + tid;
        const int rowl = slot >> 5, oct = slot & 31;
        const size_t gp = (size_t)(base + rowl) * 42;
        const float posx = (tgt[gp + 20] - lox) * sx;
        const float posy = (tgt[gp + 21] - loy) * sy;
        unsigned short v[8];
        #pragma unroll
        for (int e = 0; e < 8; e++) {
            const int ch = oct * 8 + e;
            const float pos = (ch < 128) ? posy : posx;
            const int j7 = ch & 127, fi = j7 >> 1;
            const float freq = exp2f(-(float)fi * 0.20762050593046f) * 6.283185307179586f;
            const float arg = pos * freq;
            v[e] = f2bf((j7 & 1) ? __cosf(arg) : __sinf(arg));
        }
        uint4 pk;
        pk.x = (unsigned)v[0] | ((unsigned)v[1] << 16);
        pk.y = (unsigned)v[2] | ((unsigned)v[3] << 16);
        pk.z = (unsigned)v[4] | ((unsigned)v[5] << 16);
        pk.w = (unsigned)v[6] | ((unsigned)v[7] << 16);
        *(uint4*)(sm + P_SINE + ((oct >> 2) * 4 + (rowl >> 4)) * 1024 +
                  ((rowl & 15) + 16 * (oct & 3)) * 16) = pk;
    }
    __syncthreads();

    const int mw = wid >> 1, nw = wid & 1;     // G1 roles
    const int mw5 = wid >> 2, nw5 = wid & 3;   // G2 roles

    f32x4 acc5[2][4];
    #pragma unroll
    for (int a = 0; a < 2; a++)
        #pragma unroll
        for (int s = 0; s < 4; s++) acc5[a][s] = (f32x4){0.f, 0.f, 0.f, 0.f};

    for (int chunk = 0; chunk < 8; chunk++) {
        f32x4 acc4[2];
        acc4[0] = (f32x4){0.f, 0.f, 0.f, 0.f};
        acc4[1] = (f32x4){0.f, 0.f, 0.f, 0.f};

        for (int ks = 0; ks < 2; ks++) {
            {
                const uint4* g = (const uint4*)((const char*)ws + WS_WP1 + (chunk * 2 + ks) * 16384);
                uint4* l = (uint4*)(sm + P_W);
                l[tid * 2] = g[tid * 2]; l[tid * 2 + 1] = g[tid * 2 + 1];
            }
            __syncthreads();
            #pragma unroll
            for (int ktl = 0; ktl < 4; ktl++) {
                const bf16x8 a = *(const bf16x8*)(sm + P_W + (mw * 4 + ktl) * 1024 + lane * 16);
                #pragma unroll
                for (int nj = 0; nj < 2; nj++) {
                    const bf16x8 bb = *(const bf16x8*)(sm + P_SINE +
                        ((ks * 4 + ktl) * 4 + nw * 2 + nj) * 1024 + lane * 16);
                    acc4[nj] = __builtin_amdgcn_mfma_f32_16x16x32_bf16(a, bb, acc4[nj], 0, 0, 0);
                }
            }
            __syncthreads();
        }
        // epilogue: +bp1, relu -> phc A-frags
        {
            const int choff = mw * 16 + lg * 4;
            const int ch = chunk * 64 + choff;
            const float4 bv = *(const float4*)(bp1 + ch);
            const int kt2 = choff >> 5;
            const int lane16 = l15 + 16 * ((choff & 31) >> 3);
            const int sub = (lg & 1) * 8;
            #pragma unroll
            for (int nj = 0; nj < 2; nj++) {
                const int nt = nw * 2 + nj;
                const f32x4 v = acc4[nj];
                uint2 pk;
                pk.x = pk2(fmaxf(v[0] + bv.x, 0.f), fmaxf(v[1] + bv.y, 0.f));
                pk.y = pk2(fmaxf(v[2] + bv.z, 0.f), fmaxf(v[3] + bv.w, 0.f));
                *(uint2*)(sm + P_PHC + (nt * 2 + kt2) * 1024 + lane16 * 16 + sub) = pk;
            }
        }
        for (int half = 0; half < 2; half++) {
            __syncthreads();
            {
                const uint4* g = (const uint4*)((const char*)ws + WS_WP2 + (chunk * 32 + half * 16) * 1024);
                uint4* l = (uint4*)(sm + P_W);
                l[tid * 2] = g[tid * 2]; l[tid * 2 + 1] = g[tid * 2 + 1];
            }
            __syncthreads();
            #pragma unroll
            for (int ktl = 0; ktl < 2; ktl++) {
                bf16x8 a[2];
                #pragma unroll
                for (int mi = 0; mi < 2; mi++)
                    a[mi] = *(const bf16x8*)(sm + P_PHC + ((mw5 * 2 + mi) * 2 + ktl) * 1024 + lane * 16);
                #pragma unroll
                for (int nj = 0; nj < 2; nj++) {
                    const bf16x8 bb = *(const bf16x8*)(sm + P_W + ((nw5 * 2 + nj) * 2 + ktl) * 1024 + lane * 16);
                    #pragma unroll
                    for (int mi = 0; mi < 2; mi++)
                        acc5[mi][half * 2 + nj] =
                            __builtin_amdgcn_mfma_f32_16x16x32_bf16(a[mi], bb, acc5[mi][half * 2 + nj], 0, 0, 0);
                }
            }
        }
        __syncthreads();
    }

    // final: +bp2, masked row writes
    #pragma unroll
    for (int mi = 0; mi < 2; mi++) {
        const int mt = mw5 * 2 + mi;
        #pragma unroll
        for (int s = 0; s < 4; s++) {
            const int nt = (s >> 1) * 8 + nw5 * 2 + (s & 1);
            const int ch = nt * 16 + l15;
            const float bo = bp2[ch];
            const f32x4 v = acc5[mi][s];
            #pragma unroll
            for (int r = 0; r < 4; r++) {
                const int row = base + mt * 16 + lg * 4 + r;
                out1[(size_t)row * 256 + ch] = (mask[row] != 0) ? (v[r] + bo) : 0.f;
            }
        }
    }
}

extern "C" void kernel_launch(void* const* d_in, const int* in_sizes, int n_in,
                              void* d_out, int out_size, void* d_ws, size_t ws_size,
                              hipStream_t stream) {
    const float*         tgt   = (const float*)d_in[0];
    const int*           lab   = (const int*)d_in[1];
    const unsigned char* mraw  = (const unsigned char*)d_in[2];
    const float* W1  = (const float*)d_in[3];
    const float* b1  = (const float*)d_in[4];
    const float* g1  = (const float*)d_in[5];
    const float* be1 = (const float*)d_in[6];
    const float* m1  = (const float*)d_in[7];
    const float* v1  = (const float*)d_in[8];
    const float* W2  = (const float*)d_in[9];
    const float* b2  = (const float*)d_in[10];
    const float* W3  = (const float*)d_in[11];
    const float* b3  = (const float*)d_in[12];
    const float* g2  = (const float*)d_in[13];
    const float* be2 = (const float*)d_in[14];
    const float* m2  = (const float*)d_in[15];
    const float* v2  = (const float*)d_in[16];
    const float* W4  = (const float*)d_in[17];
    const float* b4  = (const float*)d_in[18];
    const float* temb = (const float*)d_in[19];
    const float* Wp1 = (const float*)d_in[20];
    const float* bp1 = (const float*)d_in[21];
    const float* Wp2 = (const float*)d_in[22];
    const float* bp2 = (const float*)d_in[23];
    const float* pcr = (const float*)d_in[24];

    float* out0 = (float*)d_out;
    float* out1 = out0 + (size_t)NPOLY * 256;
    float* out2 = out1 + (size_t)NPOLY * 256;

    unsigned char*  maskb = (unsigned char*)d_ws;
    unsigned short* wsw   = (unsigned short*)d_ws;

    static int attr_done_proxy = 0; (void)attr_done_proxy;
    hipFuncSetAttribute(reinterpret_cast<const void*>(enc_mfma),
                        hipFuncAttributeMaxDynamicSharedMemorySize, L_TOT);

    norm_mask<<<NPOLY / 256, 256, 0, stream>>>(mraw, maskb, out2);
    prep_weights<<<960, 512, 0, stream>>>(W2, W3, W4, Wp1, Wp2, wsw);
    enc_mfma<<<NPOLY / NPB, 512, L_TOT, stream>>>(
        tgt, lab, maskb, W1, b1, g1, be1, m1, v1, b2, b3, g2, be2, m2, v2,
        b4, temb, wsw, out0);
    pe_mfma<<<NPOLY / 64, 512, 0, stream>>>(tgt, maskb, bp1, bp2, pcr, wsw, out1);
}

// Round 4
// 136.893 us; speedup vs baseline: 10.4629x; 2.6017x over previous
//
#include <hip/hip_runtime.h>

// ---------------------------------------------------------------------------
// MapEncoder, round 4: MFMA + active-polyline compaction + 2 blocks/CU.
// Block = 4 ACTIVE polylines = 80 packed point-cols (5 exact 16-tiles).
// All GEMMs transposed: D = W^T(A-operand) @ act^T(B-operand).
// Fragment convention (HW-verified m89/m91): lane&15 = M/N index, 8 contiguous
// k per lane at k-group (lane>>4)*8; D: col=lane&15, row=4*(lane>>4)+reg.
// Weights are consumed DIRECTLY from global (L2-resident, coalesced 1KB/wave
// frag reads) -> no LDS weight staging, ~9 barriers/block instead of ~30.
// ---------------------------------------------------------------------------

#define NPOLY 16384
#define NPB   4              // active polylines per block
#define NC    80             // point-cols per block
#define NT    5              // N tiles

typedef float f32x4  __attribute__((ext_vector_type(4)));
typedef short bf16x8 __attribute__((ext_vector_type(8)));

__device__ __forceinline__ unsigned short f2bf(float x) {
    union { float f; unsigned u; } v; v.f = x;
    unsigned r = v.u + 0x7FFF + ((v.u >> 16) & 1);
    return (unsigned short)(r >> 16);
}
__device__ __forceinline__ float bf2f(unsigned short s) {
    union { unsigned u; float f; } v; v.u = ((unsigned)s) << 16;
    return v.f;
}
__device__ __forceinline__ unsigned pk2(float a, float b) {
    return (unsigned)f2bf(a) | ((unsigned)f2bf(b) << 16);
}
__device__ __forceinline__ float bflo(unsigned u) {
    union { unsigned x; float f; } w; w.x = u << 16; return w.f;
}
__device__ __forceinline__ float bfhi(unsigned u) {
    union { unsigned x; float f; } w; w.x = u & 0xFFFF0000u; return w.f;
}

// ---- workspace layout (bytes) ----
#define WS_CNT  0          // int count of active polylines
#define WS_LIST 64         // u16 list[16384] of active poly ids       32768 B
#define WS_W2   33792      // 64 frags  (A-style, M=256 K=128)         65536 B
#define WS_W3   99328      // 256 frags (A-style, M=256 K=512)        262144 B
#define WS_W4   361472     // 128 frags (B-style, N=256 K=256)        131072 B
#define WS_WP1  492544     // 256 frags (A-style, M=512 K=256)        262144 B
#define WS_WP2  754688     // 256 frags (B-style, N=256 K=512)        262144 B
// end 1016832

// ---- enc LDS layout (dynamic, 65536 B total) ----
#define L_CAT   0          // 25 frags h B-operand (kt0..4..7, nt0..4) 25600.. full 40960
                           //   (K=256 -> 8 kt x 5 nt = 40 frags)      40960
                           //   overlays: feat f32[80][8] (2560, P0/P1)
                           //             runs bf16[20][256] (10240, P5/P6)
#define L_H1    40960      // 20 frags h1 B-operand; later h2c A-frags 20480
#define L_H2C   40960
#define L_POOL  61440      // pooled bf16 [4][256]                      2048
#define L_SC    63488      // sc2 f32[256]                              1024
#define L_OF    64512      // (b3 - m2)*sc + be2 f32[256]               1024
#define L_TOT   65536

// ---------------------------------------------------------------------------
// mask normalization (byte-bool or int32) + compaction + out2 + zero inactive
// out0 rows. 64 blocks x 256 threads.
// ---------------------------------------------------------------------------
__global__ __launch_bounds__(256) void norm_mask(
    const unsigned char* __restrict__ mraw, float* __restrict__ out2,
    unsigned short* __restrict__ list, int* __restrict__ cnt,
    float* __restrict__ out0)
{
    __shared__ int s_nz;
    __shared__ unsigned char s_v[256];
    const int tid = threadIdx.x;
    if (tid == 0) s_nz = 0;
    __syncthreads();
    int local = 0;
    for (int j = 0; j < 64; j++) {                 // scan first 16KB
        const int i = tid * 64 + j;
        if ((i & 3) != 0) local |= mraw[i];
    }
    if (local) atomicOr(&s_nz, 1);
    __syncthreads();
    const bool isByte = (s_nz != 0);               // int32 0/1 LE: bytes i%4!=0 all 0
    const int i = blockIdx.x * 256 + tid;
    const unsigned char v = isByte ? (mraw[i] != 0) : (((const int*)mraw)[i] != 0);
    out2[i] = v ? 0.0f : 1.0f;
    s_v[tid] = v;
    if (v) { const int pos = atomicAdd(cnt, 1); list[pos] = (unsigned short)i; }
    __syncthreads();
    // zero out0 rows for inactive polys, coalesced (32 threads per row)
    const float4 z = {0.f, 0.f, 0.f, 0.f};
    for (int r8 = 0; r8 < 32; r8++) {
        const int row = r8 * 8 + (tid >> 5);
        if (!s_v[row]) {
            float4* dst = (float4*)(out0 + (size_t)(blockIdx.x * 256 + row) * 256);
            dst[tid & 31] = z;
            dst[(tid & 31) + 32] = z;
        }
    }
}

// ---------------------------------------------------------------------------
// weight prep: f32 -> bf16, fragment-linear into ws. One block per fragment.
// ---------------------------------------------------------------------------
__global__ __launch_bounds__(512) void prep_weights(
    const float* __restrict__ W2, const float* __restrict__ W3,
    const float* __restrict__ W4, const float* __restrict__ Wp1,
    const float* __restrict__ Wp2, unsigned short* __restrict__ wsu)
{
    const int bid = blockIdx.x;
    const float* src; int mode, KS, ld, fid; size_t dst;
    if      (bid < 64)  { src = W2;  mode = 0; KS = 0; ld = 256; fid = bid;       dst = WS_W2;  }
    else if (bid < 320) { src = W3;  mode = 1; KS = 4; ld = 256; fid = bid - 64;  dst = WS_W3;  }
    else if (bid < 448) { src = W4;  mode = 2; KS = 0; ld = 256; fid = bid - 320; dst = WS_W4;  }
    else if (bid < 704) { src = Wp1; mode = 1; KS = 2; ld = 512; fid = bid - 448; dst = WS_WP1; }
    else                { src = Wp2; mode = 2; KS = 0; ld = 256; fid = bid - 704; dst = WS_WP2; }

    int mt, kt;
    if (mode == 0) { mt = fid & 15; kt = fid >> 4; }
    else if (mode == 1) {
        const int low = fid & 15, hi = fid >> 4;
        mt = (hi / KS) * 4 + (low >> 2);
        kt = (hi % KS) * 4 + (low & 3);
    } else {                       // mode 2 (B-style)
        const int low = fid & 31;
        kt = (fid >> 5) * 2 + (low & 1);
        mt = ((low >> 4) & 1) * 8 + ((low >> 1) & 7);
    }
    const int t   = threadIdx.x;
    const int l15 = t & 15, e = (t >> 4) & 7, lg = (t >> 7) & 3;
    const int m = mt * 16 + l15;
    const int k = kt * 32 + lg * 8 + e;
    wsu[dst / 2 + (size_t)fid * 512 + (l15 + 16 * lg) * 8 + e] = f2bf(src[(size_t)k * ld + m]);
}

// ---------------------------------------------------------------------------
// main encoder (active polylines only). 512 threads = 8 waves, 64 KB LDS.
// ---------------------------------------------------------------------------
__global__ __launch_bounds__(512, 4) void enc_mfma(
    const float* __restrict__ tgt, const int* __restrict__ label,
    const unsigned short* __restrict__ list, const int* __restrict__ cnt,
    const float* __restrict__ W1, const float* __restrict__ b1,
    const float* __restrict__ g1, const float* __restrict__ be1,
    const float* __restrict__ m1, const float* __restrict__ v1,
    const float* __restrict__ b2, const float* __restrict__ b3,
    const float* __restrict__ g2, const float* __restrict__ be2,
    const float* __restrict__ m2, const float* __restrict__ v2,
    const float* __restrict__ b4, const float* __restrict__ temb,
    const char* __restrict__ wsb, float* __restrict__ out0)
{
    extern __shared__ char smem[];
    const int nact  = cnt[0];
    const int bbase = blockIdx.x * NPB;
    if (bbase >= nact) return;

    const int tid  = threadIdx.x;
    const int wid  = tid >> 6;
    const int lane = tid & 63;
    const int l15  = lane & 15, lg = lane >> 4;

    // ---------- P0: feat (CAT overlay) + folded bn2 params ----------
    if (tid < NC) {
        const int c = tid, pl = c / 20, p = c - pl * 20;
        const int gpoly = list[min(bbase + pl, nact - 1)];
        const size_t gp = (size_t)gpoly * 42;
        const float px = tgt[gp + p * 2],     py = tgt[gp + p * 2 + 1];
        const float qx = tgt[gp + p * 2 + 2], qy = tgt[gp + p * 2 + 3];
        const float cx = tgt[gp + 20],        cy = tgt[gp + 21];
        const float vx = qx - px, vy = qy - py;
        const float inv = 1.0f / (sqrtf(vx * vx + vy * vy) + 1.0f + 1e-6f); // active: +1
        float* f = (float*)(smem + L_CAT + c * 32);
        f[0] = px - cx; f[1] = py - cy; f[2] = vx; f[3] = vy;
        f[4] = vx * inv; f[5] = vy * inv; f[6] = 0.f; f[7] = 0.f;
    }
    if (tid < 256) {
        const float sc = rsqrtf(v2[tid] + 1e-5f) * g2[tid];
        ((float*)(smem + L_SC))[tid] = sc;
        ((float*)(smem + L_OF))[tid] = (b3[tid] - m2[tid]) * sc + be2[tid];
    }
    __syncthreads();

    // ---------- P1: h1 = relu(bn1(feat@W1+b1)) -> B-frags ----------
    {
        const int ch = tid & 127, cblk = tid >> 7;
        float w[6];
        #pragma unroll
        for (int j = 0; j < 6; j++) w[j] = W1[j * 128 + ch];
        const float sc1  = rsqrtf(v1[ch] + 1e-5f) * g1[ch];
        const float off1 = (b1[ch] - m1[ch]) * sc1 + be1[ch];
        const int kt = ch >> 5, koff = ch & 31;
        const int lane16 = 16 * (koff >> 3);
        #pragma unroll 4
        for (int i = 0; i < 20; i++) {
            const int c = i * 4 + cblk;
            const float* f = (const float*)(smem + L_CAT + c * 32);
            float a = 0.f;
            #pragma unroll
            for (int j = 0; j < 6; j++) a = fmaf(f[j], w[j], a);
            a = fmaxf(fmaf(a, sc1, off1), 0.f);
            *(unsigned short*)(smem + L_H1 + (kt * NT + (c >> 4)) * 1024 +
                               ((c & 15) + lane16) * 16 + (koff & 7) * 2) = f2bf(a);
        }
    }
    __syncthreads();

    // ---------- S3: h^T = W2^T @ h1^T (M=256,N=80,K=128); wave = 2 mt ----
    {
        f32x4 acc[2][5];
        #pragma unroll
        for (int a = 0; a < 2; a++)
            #pragma unroll
            for (int b = 0; b < 5; b++) acc[a][b] = (f32x4){0.f, 0.f, 0.f, 0.f};

        #pragma unroll
        for (int kt = 0; kt < 4; kt++) {
            bf16x8 a[2];
            #pragma unroll
            for (int mi = 0; mi < 2; mi++)
                a[mi] = *(const bf16x8*)(wsb + WS_W2 +
                         (size_t)(kt * 16 + wid * 2 + mi) * 1024 + lane * 16);
            #pragma unroll
            for (int nj = 0; nj < 5; nj++) {
                const bf16x8 bb = *(const bf16x8*)(smem + L_H1 + (kt * NT + nj) * 1024 + lane * 16);
                #pragma unroll
                for (int mi = 0; mi < 2; mi++)
                    acc[mi][nj] = __builtin_amdgcn_mfma_f32_16x16x32_bf16(a[mi], bb, acc[mi][nj], 0, 0, 0);
            }
        }
        // epilogue: + b2 -> CAT B-frags
        #pragma unroll
        for (int mi = 0; mi < 2; mi++) {
            const int mt = wid * 2 + mi, chb = mt * 16 + lg * 4;
            const float4 bv = *(const float4*)(b2 + chb);
            const int kt = chb >> 5, koff = chb & 31;
            const int lane16 = l15 + 16 * (koff >> 3);
            #pragma unroll
            for (int nj = 0; nj < 5; nj++) {
                const f32x4 v = acc[mi][nj];
                uint2 pk;
                pk.x = pk2(v[0] + bv.x, v[1] + bv.y);
                pk.y = pk2(v[2] + bv.z, v[3] + bv.w);
                *(uint2*)(smem + L_CAT + (kt * NT + nj) * 1024 + lane16 * 16 + (koff & 7) * 2) = pk;
            }
        }
    }
    __syncthreads();

    // ---------- P3: pooled[poly][ch] = max_p h  (b128 reads) ----------
    if (tid < 128) {
        const int pl = tid >> 5, grp = tid & 31;       // grp = ch octet
        const int fragbase = (grp >> 2) * NT;          // kt*NT
        const int off16 = 16 * (grp & 3);
        float mx[8];
        #pragma unroll
        for (int e = 0; e < 8; e++) mx[e] = -3.0e38f;
        #pragma unroll 4
        for (int p = 0; p < 20; p++) {
            const int c = pl * 20 + p;
            const uint4 v = *(const uint4*)(smem + L_CAT +
                (fragbase + (c >> 4)) * 1024 + ((c & 15) + off16) * 16);
            mx[0] = fmaxf(mx[0], bflo(v.x)); mx[1] = fmaxf(mx[1], bfhi(v.x));
            mx[2] = fmaxf(mx[2], bflo(v.y)); mx[3] = fmaxf(mx[3], bfhi(v.y));
            mx[4] = fmaxf(mx[4], bflo(v.z)); mx[5] = fmaxf(mx[5], bfhi(v.z));
            mx[6] = fmaxf(mx[6], bflo(v.w)); mx[7] = fmaxf(mx[7], bfhi(v.w));
        }
        uint4 pk;
        pk.x = pk2(mx[0], mx[1]); pk.y = pk2(mx[2], mx[3]);
        pk.z = pk2(mx[4], mx[5]); pk.w = pk2(mx[6], mx[7]);
        *(uint4*)(smem + L_POOL + pl * 512 + grp * 16) = pk;
    }
    __syncthreads();

    // pooled B-operand per-lane bases
    unsigned pbase[5];
    #pragma unroll
    for (int nj = 0; nj < 5; nj++) {
        const int c = nj * 16 + l15;
        pbase[nj] = L_POOL + (unsigned)(c / 20) * 512 + lg * 16;
    }

    // ---------- P4: 2 chunks of 128 out-ch: S4 (K=512) fused w/ S5 --------
    f32x4 acc5[5][2];
    #pragma unroll
    for (int a = 0; a < 5; a++) {
        acc5[a][0] = (f32x4){0.f, 0.f, 0.f, 0.f};
        acc5[a][1] = (f32x4){0.f, 0.f, 0.f, 0.f};
    }

    #pragma unroll 1
    for (int chunk = 0; chunk < 2; chunk++) {
        f32x4 acc4[5];
        #pragma unroll
        for (int s = 0; s < 5; s++) acc4[s] = (f32x4){0.f, 0.f, 0.f, 0.f};
        const int mtg = chunk * 8 + wid;
        const int fhi = (mtg >> 2) * 4, flo = (mtg & 3) * 4;

        // S4: A from global (1-deep pipeline), B from CAT/POOL LDS
        bf16x8 a_cur = *(const bf16x8*)(wsb + WS_W3 + (size_t)(fhi * 16 + flo) * 1024 + lane * 16);
        #pragma unroll
        for (int ktg = 0; ktg < 16; ktg++) {
            bf16x8 a_nxt;
            if (ktg < 15) {
                const int kn = ktg + 1;
                a_nxt = *(const bf16x8*)(wsb + WS_W3 +
                        (size_t)((fhi + (kn >> 2)) * 16 + flo + (kn & 3)) * 1024 + lane * 16);
            }
            #pragma unroll
            for (int nj = 0; nj < 5; nj++) {
                bf16x8 bb;
                if (ktg < 8)
                    bb = *(const bf16x8*)(smem + L_CAT + (ktg * NT + nj) * 1024 + lane * 16);
                else
                    bb = *(const bf16x8*)(smem + pbase[nj] + (ktg - 8) * 64);
                acc4[nj] = __builtin_amdgcn_mfma_f32_16x16x32_bf16(a_cur, bb, acc4[nj], 0, 0, 0);
            }
            a_cur = a_nxt;
        }
        // epilogue: bn2+relu -> h2c A-frags (reuses H1 region)
        {
            const int choff = wid * 16 + lg * 4;          // 0..127 in chunk
            const int chg = chunk * 128 + choff;
            const float4 scv = *(const float4*)(smem + L_SC + chg * 4);
            const float4 ofv = *(const float4*)(smem + L_OF + chg * 4);
            const int kt2 = choff >> 5;
            const int lane16 = l15 + 16 * ((choff & 31) >> 3);
            const int sub = (lg & 1) * 8;
            #pragma unroll
            for (int nj = 0; nj < 5; nj++) {
                const f32x4 v = acc4[nj];
                uint2 pk;
                pk.x = pk2(fmaxf(fmaf(v[0], scv.x, ofv.x), 0.f),
                           fmaxf(fmaf(v[1], scv.y, ofv.y), 0.f));
                pk.y = pk2(fmaxf(fmaf(v[2], scv.z, ofv.z), 0.f),
                           fmaxf(fmaf(v[3], scv.w, ofv.w), 0.f));
                *(uint2*)(smem + L_H2C + (nj * 4 + kt2) * 1024 + lane16 * 16 + sub) = pk;
            }
        }
        __syncthreads();

        // S5: acc5 += h2c @ W4[chunk]; A from LDS, B from global
        #pragma unroll
        for (int kt2 = 0; kt2 < 4; kt2++) {
            const int ktB = chunk * 4 + kt2;
            bf16x8 b[2];
            #pragma unroll
            for (int njb = 0; njb < 2; njb++) {
                const int ntB = wid * 2 + njb;
                const int fid = (ktB >> 1) * 32 + ((ntB >> 3) & 1) * 16 + (ntB & 7) * 2 + (ktB & 1);
                b[njb] = *(const bf16x8*)(wsb + WS_W4 + (size_t)fid * 1024 + lane * 16);
            }
            #pragma unroll
            for (int mi = 0; mi < 5; mi++) {
                const bf16x8 a = *(const bf16x8*)(smem + L_H2C + (mi * 4 + kt2) * 1024 + lane * 16);
                acc5[mi][0] = __builtin_amdgcn_mfma_f32_16x16x32_bf16(a, b[0], acc5[mi][0], 0, 0, 0);
                acc5[mi][1] = __builtin_amdgcn_mfma_f32_16x16x32_bf16(a, b[1], acc5[mi][1], 0, 0, 0);
            }
        }
        __syncthreads();
    }

    // ---------- P5: 4-col run maxes -> CAT overlay ----------
    #pragma unroll
    for (int mi = 0; mi < 5; mi++) {
        const int run = mi * 4 + lg;                    // 4 point-cols per run
        #pragma unroll
        for (int njb = 0; njb < 2; njb++) {
            const int ch = (wid * 2 + njb) * 16 + l15;
            const f32x4 v = acc5[mi][njb];
            const float m4 = fmaxf(fmaxf(v[0], v[1]), fmaxf(v[2], v[3]));
            *(unsigned short*)(smem + L_CAT + run * 512 + ch * 2) = f2bf(m4);
        }
    }
    __syncthreads();

    // ---------- P6: final max + b4 + type_emb ----------
    #pragma unroll
    for (int i = 0; i < 2; i++) {
        const int idx = i * 512 + tid, pl = idx >> 8, ch = idx & 255;
        if (bbase + pl < nact) {
            const int gpoly = list[bbase + pl];
            float mx = -3.0e38f;
            #pragma unroll
            for (int j = 0; j < 5; j++)
                mx = fmaxf(mx, bf2f(*(const unsigned short*)(smem + L_CAT +
                        (pl * 5 + j) * 512 + ch * 2)));
            out0[(size_t)gpoly * 256 + ch] = mx + b4[ch] + temb[label[gpoly] * 256 + ch];
        }
    }
}

// ---------------------------------------------------------------------------
// PE: pe = relu(sine@Wp1+bp1)@Wp2+bp2, masked via out2. 64 rows/block.
// ---------------------------------------------------------------------------
#define P_SINE 0
#define P_PHC  32768
#define P_W    40960

__global__ __launch_bounds__(512, 2) void pe_mfma(
    const float* __restrict__ tgt, const float* __restrict__ out2,
    const float* __restrict__ bp1, const float* __restrict__ bp2,
    const float* __restrict__ pcr, const char* __restrict__ wsb,
    float* __restrict__ out1)
{
    __shared__ __align__(16) char sm[57344];
    const int tid  = threadIdx.x;
    const int wid  = tid >> 6;
    const int lane = tid & 63;
    const int l15  = lane & 15, lg = lane >> 4;
    const int base = blockIdx.x * 64;

    const float lox = pcr[0], loy = pcr[1];
    const float sx = 1.0f / (pcr[3] - pcr[0]), sy = 1.0f / (pcr[4] - pcr[1]);

    #pragma unroll
    for (int i = 0; i < 4; i++) {
        const int slot = i * 512 + tid;
        const int rowl = slot >> 5, oct = slot & 31;
        const size_t gp = (size_t)(base + rowl) * 42;
        const float posx = (tgt[gp + 20] - lox) * sx;
        const float posy = (tgt[gp + 21] - loy) * sy;
        unsigned short v[8];
        #pragma unroll
        for (int e = 0; e < 8; e++) {
            const int ch = oct * 8 + e;
            const float pos = (ch < 128) ? posy : posx;
            const int j7 = ch & 127, fi = j7 >> 1;
            const float freq = exp2f(-(float)fi * 0.20762050593046f) * 6.283185307179586f;
            const float arg = pos * freq;
            v[e] = f2bf((j7 & 1) ? __cosf(arg) : __sinf(arg));
        }
        uint4 pk;
        pk.x = (unsigned)v[0] | ((unsigned)v[1] << 16);
        pk.y = (unsigned)v[2] | ((unsigned)v[3] << 16);
        pk.z = (unsigned)v[4] | ((unsigned)v[5] << 16);
        pk.w = (unsigned)v[6] | ((unsigned)v[7] << 16);
        *(uint4*)(sm + P_SINE + ((oct >> 2) * 4 + (rowl >> 4)) * 1024 +
                  ((rowl & 15) + 16 * (oct & 3)) * 16) = pk;
    }
    __syncthreads();

    const int mw = wid >> 1, nw = wid & 1;
    const int mw5 = wid >> 2, nw5 = wid & 3;

    f32x4 acc5[2][4];
    #pragma unroll
    for (int a = 0; a < 2; a++)
        #pragma unroll
        for (int s = 0; s < 4; s++) acc5[a][s] = (f32x4){0.f, 0.f, 0.f, 0.f};

    #pragma unroll 1
    for (int chunk = 0; chunk < 8; chunk++) {
        f32x4 acc4[2];
        acc4[0] = (f32x4){0.f, 0.f, 0.f, 0.f};
        acc4[1] = (f32x4){0.f, 0.f, 0.f, 0.f};

        // Wp1 A-frags straight from global
        #pragma unroll
        for (int ktg = 0; ktg < 8; ktg++) {
            const int mtg = chunk * 4 + mw;            // Wp1: M=512 (32 mt), wave mt = chunk*4+mw
            const int fid = ((mtg >> 2) * 2 + (ktg >> 2)) * 16 + (mtg & 3) * 4 + (ktg & 3);
            const bf16x8 a = *(const bf16x8*)(wsb + WS_WP1 + (size_t)fid * 1024 + lane * 16);
            #pragma unroll
            for (int nj = 0; nj < 2; nj++) {
                const bf16x8 bb = *(const bf16x8*)(sm + P_SINE +
                    (ktg * 4 + nw * 2 + nj) * 1024 + lane * 16);
                acc4[nj] = __builtin_amdgcn_mfma_f32_16x16x32_bf16(a, bb, acc4[nj], 0, 0, 0);
            }
        }
        // epilogue: +bp1, relu -> phc A-frags
        {
            const int choff = mw * 16 + lg * 4;
            const int ch = chunk * 64 + choff;
            const float4 bv = *(const float4*)(bp1 + ch);
            const int kt2 = choff >> 5;
            const int lane16 = l15 + 16 * ((choff & 31) >> 3);
            const int sub = (lg & 1) * 8;
            #pragma unroll
            for (int nj = 0; nj < 2; nj++) {
                const int nt = nw * 2 + nj;
                const f32x4 v = acc4[nj];
                uint2 pk;
                pk.x = pk2(fmaxf(v[0] + bv.x, 0.f), fmaxf(v[1] + bv.y, 0.f));
                pk.y = pk2(fmaxf(v[2] + bv.z, 0.f), fmaxf(v[3] + bv.w, 0.f));
                *(uint2*)(sm + P_PHC + (nt * 2 + kt2) * 1024 + lane16 * 16 + sub) = pk;
            }
        }
        __syncthreads();
        // Wp2 B-frags from global
        #pragma unroll
        for (int ktl = 0; ktl < 2; ktl++) {
            const int ktB = chunk * 2 + ktl;
            bf16x8 a[2];
            #pragma unroll
            for (int mi = 0; mi < 2; mi++)
                a[mi] = *(const bf16x8*)(sm + P_PHC + ((mw5 * 2 + mi) * 2 + ktl) * 1024 + lane * 16);
            #pragma unroll
            for (int njj = 0; njj < 4; njj++) {
                const int ntB = ((njj >> 1) * 8) + nw5 * 2 + (njj & 1);
                const int fid = (ktB >> 1) * 32 + ((ntB >> 3) & 1) * 16 + (ntB & 7) * 2 + (ktB & 1);
                const bf16x8 bb = *(const bf16x8*)(wsb + WS_WP2 + (size_t)fid * 1024 + lane * 16);
                #pragma unroll
                for (int mi = 0; mi < 2; mi++)
                    acc5[mi][njj] = __builtin_amdgcn_mfma_f32_16x16x32_bf16(a[mi], bb, acc5[mi][njj], 0, 0, 0);
            }
        }
        __syncthreads();
    }

    #pragma unroll
    for (int mi = 0; mi < 2; mi++) {
        const int mt = mw5 * 2 + mi;
        #pragma unroll
        for (int s = 0; s < 4; s++) {
            const int nt = (s >> 1) * 8 + nw5 * 2 + (s & 1);
            const int ch = nt * 16 + l15;
            const float bo = bp2[ch];
            const f32x4 v = acc5[mi][s];
            #pragma unroll
            for (int r = 0; r < 4; r++) {
                const int row = base + mt * 16 + lg * 4 + r;
                out1[(size_t)row * 256 + ch] = (out2[row] == 0.0f) ? (v[r] + bo) : 0.f;
            }
        }
    }
}

extern "C" void kernel_launch(void* const* d_in, const int* in_sizes, int n_in,
                              void* d_out, int out_size, void* d_ws, size_t ws_size,
                              hipStream_t stream) {
    const float*         tgt   = (const float*)d_in[0];
    const int*           lab   = (const int*)d_in[1];
    const unsigned char* mraw  = (const unsigned char*)d_in[2];
    const float* W1  = (const float*)d_in[3];
    const float* b1  = (const float*)d_in[4];
    const float* g1  = (const float*)d_in[5];
    const float* be1 = (const float*)d_in[6];
    const float* m1  = (const float*)d_in[7];
    const float* v1  = (const float*)d_in[8];
    const float* W2  = (const float*)d_in[9];
    const float* b2  = (const float*)d_in[10];
    const float* W3  = (const float*)d_in[11];
    const float* b3  = (const float*)d_in[12];
    const float* g2  = (const float*)d_in[13];
    const float* be2 = (const float*)d_in[14];
    const float* m2  = (const float*)d_in[15];
    const float* v2  = (const float*)d_in[16];
    const float* W4  = (const float*)d_in[17];
    const float* b4  = (const float*)d_in[18];
    const float* temb = (const float*)d_in[19];
    const float* Wp1 = (const float*)d_in[20];
    const float* bp1 = (const float*)d_in[21];
    const float* Wp2 = (const float*)d_in[22];
    const float* bp2 = (const float*)d_in[23];
    const float* pcr = (const float*)d_in[24];

    float* out0 = (float*)d_out;
    float* out1 = out0 + (size_t)NPOLY * 256;
    float* out2 = out1 + (size_t)NPOLY * 256;

    char*           wsb  = (char*)d_ws;
    int*            cnt  = (int*)(wsb + WS_CNT);
    unsigned short* list = (unsigned short*)(wsb + WS_LIST);
    unsigned short* wsu  = (unsigned short*)d_ws;

    hipFuncSetAttribute(reinterpret_cast<const void*>(enc_mfma),
                        hipFuncAttributeMaxDynamicSharedMemorySize, L_TOT);

    hipMemsetAsync(cnt, 0, 4, stream);
    norm_mask<<<NPOLY / 256, 256, 0, stream>>>(mraw, out2, list, cnt, out0);
    prep_weights<<<960, 512, 0, stream>>>(W2, W3, W4, Wp1, Wp2, wsu);
    enc_mfma<<<NPOLY / NPB, 512, L_TOT, stream>>>(
        tgt, lab, list, cnt, W1, b1, g1, be1, m1, v1, b2, b3, g2, be2, m2, v2,
        b4, temb, wsb, out0);
    pe_mfma<<<NPOLY / 64, 512, 0, stream>>>(tgt, out2, bp1, bp2, pcr, wsb, out1);
}

// Round 5
// 120.555 us; speedup vs baseline: 11.8808x; 1.1355x over previous
//
#include <hip/hip_runtime.h>

// ---------------------------------------------------------------------------
// MapEncoder, round 5: MFMA + compaction + pooled-dedup + deep prefetch.
// Block = 4 ACTIVE polylines = 80 packed point-cols (5 exact 16-tiles).
// Fragment convention (HW-verified m89/m91): lane&15 = M/N index, 8 contiguous
// k per lane at k-group (lane>>4)*8; D: col=lane&15, row=4*(lane>>4)+reg.
// ---------------------------------------------------------------------------

#define NPOLY 16384
#define NPB   4
#define NC    80
#define NT    5

typedef float f32x4  __attribute__((ext_vector_type(4)));
typedef short bf16x8 __attribute__((ext_vector_type(8)));

__device__ __forceinline__ unsigned short f2bf(float x) {
    union { float f; unsigned u; } v; v.f = x;
    unsigned r = v.u + 0x7FFF + ((v.u >> 16) & 1);
    return (unsigned short)(r >> 16);
}
__device__ __forceinline__ float bf2f(unsigned short s) {
    union { unsigned u; float f; } v; v.u = ((unsigned)s) << 16;
    return v.f;
}
// single-instruction packed f32x2 -> bf16x2 (RNE), lo=a hi=b
__device__ __forceinline__ unsigned cvtpk(float a, float b) {
    unsigned r;
    asm("v_cvt_pk_bf16_f32 %0, %1, %2" : "=v"(r) : "v"(a), "v"(b));
    return r;
}
__device__ __forceinline__ float bflo(unsigned u) {
    union { unsigned x; float f; } w; w.x = u << 16; return w.f;
}
__device__ __forceinline__ float bfhi(unsigned u) {
    union { unsigned x; float f; } w; w.x = u & 0xFFFF0000u; return w.f;
}

// ---- workspace layout (bytes) ----
#define WS_CNT  0
#define WS_LIST 64         // u16 list[16384]
#define WS_W2   33792      // 64 frags  (A-style, M=256 K=128)
#define WS_W3   99328      // 256 frags (A-style, M=256 K=512)
#define WS_W4   361472     // 128 frags (B-style, N=256 K=256)
#define WS_WP1  492544     // 256 frags (A-style, M=512 K=256)
#define WS_WP2  754688     // 256 frags (B-style, N=256 K=512)

// ---- enc LDS layout (dynamic, bytes) ----
#define L_CAT   0          // 40 frags: h B-operand (kt0..7, nt0..4)    40960
                           //   overlays: feat f32[80] stride 36B (P0/P1)
                           //             runs bf16[20][256] (P5/P6)
#define L_H1    40960      // 20 frags h1 B-op; later h2c A-frags       20480
#define L_H2C   40960
#define L_PFRAG 61440      // 8 frags: pooled B-operand                  8192
#define L_SC    69632      // sc2 f32[256]                               1024
#define L_OF    70656      // (b3-m2)*sc+be2 f32[256]                    1024
#define L_APOF  71680      // apof f32[4][256]                           4096
#define L_TOT   75776

// ---------------------------------------------------------------------------
__global__ __launch_bounds__(256) void norm_mask(
    const unsigned char* __restrict__ mraw, float* __restrict__ out2,
    unsigned short* __restrict__ list, int* __restrict__ cnt,
    float* __restrict__ out0)
{
    __shared__ int s_nz;
    __shared__ unsigned char s_v[256];
    const int tid = threadIdx.x;
    if (tid == 0) s_nz = 0;
    __syncthreads();
    int local = 0;
    for (int j = 0; j < 64; j++) {
        const int i = tid * 64 + j;
        if ((i & 3) != 0) local |= mraw[i];
    }
    if (local) atomicOr(&s_nz, 1);
    __syncthreads();
    const bool isByte = (s_nz != 0);
    const int i = blockIdx.x * 256 + tid;
    const unsigned char v = isByte ? (mraw[i] != 0) : (((const int*)mraw)[i] != 0);
    out2[i] = v ? 0.0f : 1.0f;
    s_v[tid] = v;
    if (v) { const int pos = atomicAdd(cnt, 1); list[pos] = (unsigned short)i; }
    __syncthreads();
    const float4 z = {0.f, 0.f, 0.f, 0.f};
    for (int r8 = 0; r8 < 32; r8++) {
        const int row = r8 * 8 + (tid >> 5);
        if (!s_v[row]) {
            float4* dst = (float4*)(out0 + (size_t)(blockIdx.x * 256 + row) * 256);
            dst[tid & 31] = z;
            dst[(tid & 31) + 32] = z;
        }
    }
}

// ---------------------------------------------------------------------------
__global__ __launch_bounds__(512) void prep_weights(
    const float* __restrict__ W2, const float* __restrict__ W3,
    const float* __restrict__ W4, const float* __restrict__ Wp1,
    const float* __restrict__ Wp2, unsigned short* __restrict__ wsu)
{
    const int bid = blockIdx.x;
    const float* src; int mode, KS, ld, fid; size_t dst;
    if      (bid < 64)  { src = W2;  mode = 0; KS = 0; ld = 256; fid = bid;       dst = WS_W2;  }
    else if (bid < 320) { src = W3;  mode = 1; KS = 4; ld = 256; fid = bid - 64;  dst = WS_W3;  }
    else if (bid < 448) { src = W4;  mode = 2; KS = 0; ld = 256; fid = bid - 320; dst = WS_W4;  }
    else if (bid < 704) { src = Wp1; mode = 1; KS = 2; ld = 512; fid = bid - 448; dst = WS_WP1; }
    else                { src = Wp2; mode = 2; KS = 0; ld = 256; fid = bid - 704; dst = WS_WP2; }

    int mt, kt;
    if (mode == 0) { mt = fid & 15; kt = fid >> 4; }
    else if (mode == 1) {
        const int low = fid & 15, hi = fid >> 4;
        mt = (hi / KS) * 4 + (low >> 2);
        kt = (hi % KS) * 4 + (low & 3);
    } else {
        const int low = fid & 31;
        kt = (fid >> 5) * 2 + (low & 1);
        mt = ((low >> 4) & 1) * 8 + ((low >> 1) & 7);
    }
    const int t   = threadIdx.x;
    const int l15 = t & 15, e = (t >> 4) & 7, lg = (t >> 7) & 3;
    const int m = mt * 16 + l15;
    const int k = kt * 32 + lg * 8 + e;
    wsu[dst / 2 + (size_t)fid * 512 + (l15 + 16 * lg) * 8 + e] = f2bf(src[(size_t)k * ld + m]);
}

// ---------------------------------------------------------------------------
// main encoder (active polylines only). 512 threads = 8 waves.
// ---------------------------------------------------------------------------
__global__ __launch_bounds__(512, 4) void enc_mfma(
    const float* __restrict__ tgt, const int* __restrict__ label,
    const unsigned short* __restrict__ list, const int* __restrict__ cnt,
    const float* __restrict__ W1, const float* __restrict__ b1,
    const float* __restrict__ g1, const float* __restrict__ be1,
    const float* __restrict__ m1, const float* __restrict__ v1,
    const float* __restrict__ b2, const float* __restrict__ b3,
    const float* __restrict__ g2, const float* __restrict__ be2,
    const float* __restrict__ m2, const float* __restrict__ v2,
    const float* __restrict__ b4, const float* __restrict__ temb,
    const char* __restrict__ wsb, float* __restrict__ out0)
{
    extern __shared__ char smem[];
    const int nact  = cnt[0];
    const int bbase = blockIdx.x * NPB;
    if (bbase >= nact) return;

    const int tid  = threadIdx.x;
    const int wid  = tid >> 6;
    const int lane = tid & 63;
    const int l15  = lane & 15, lg = lane >> 4;

    // ---------- P0: feat (padded 36B rows, CAT overlay) + bn2 folded ------
    if (tid < NC) {
        const int c = tid, pl = c / 20, p = c - pl * 20;
        const int gpoly = list[min(bbase + pl, nact - 1)];
        const size_t gp = (size_t)gpoly * 42;
        const float px = tgt[gp + p * 2],     py = tgt[gp + p * 2 + 1];
        const float qx = tgt[gp + p * 2 + 2], qy = tgt[gp + p * 2 + 3];
        const float cx = tgt[gp + 20],        cy = tgt[gp + 21];
        const float vx = qx - px, vy = qy - py;
        const float inv = 1.0f / (sqrtf(vx * vx + vy * vy) + 1.0f + 1e-6f);
        float* f = (float*)(smem + L_CAT + c * 36);
        f[0] = px - cx; f[1] = py - cy; f[2] = vx; f[3] = vy;
        f[4] = vx * inv; f[5] = vy * inv;
    }
    if (tid < 256) {
        const float sc = rsqrtf(v2[tid] + 1e-5f) * g2[tid];
        ((float*)(smem + L_SC))[tid] = sc;
        ((float*)(smem + L_OF))[tid] = (b3[tid] - m2[tid]) * sc + be2[tid];
    }
    __syncthreads();

    // ---------- P1: h1 = relu(bn1(feat@W1+b1)) -> B-frags ----------
    {
        const int ch = tid & 127, cblk = tid >> 7;
        float w[6];
        #pragma unroll
        for (int j = 0; j < 6; j++) w[j] = W1[j * 128 + ch];
        const float sc1  = rsqrtf(v1[ch] + 1e-5f) * g1[ch];
        const float off1 = (b1[ch] - m1[ch]) * sc1 + be1[ch];
        const int kt = ch >> 5, koff = ch & 31;
        const int lane16 = 16 * (koff >> 3);
        #pragma unroll 4
        for (int i = 0; i < 20; i++) {
            const int c = i * 4 + cblk;
            const float* f = (const float*)(smem + L_CAT + c * 36);
            float a = 0.f;
            #pragma unroll
            for (int j = 0; j < 6; j++) a = fmaf(f[j], w[j], a);
            a = fmaxf(fmaf(a, sc1, off1), 0.0f);
            *(unsigned short*)(smem + L_H1 + (kt * NT + (c >> 4)) * 1024 +
                               ((c & 15) + lane16) * 16 + (koff & 7) * 2) = f2bf(a);
        }
    }
    __syncthreads();

    // ---------- S3: h^T = W2^T @ h1^T (M=256,N=80,K=128) ----------
    {
        bf16x8 a8[8];                      // all 8 A-frags up front
        #pragma unroll
        for (int kt = 0; kt < 4; kt++) {
            #pragma unroll
            for (int mi = 0; mi < 2; mi++)
                a8[kt * 2 + mi] = *(const bf16x8*)(wsb + WS_W2 +
                    (size_t)(kt * 16 + wid * 2 + mi) * 1024 + lane * 16);
        }
        f32x4 acc[2][5];
        #pragma unroll
        for (int a = 0; a < 2; a++)
            #pragma unroll
            for (int b = 0; b < 5; b++) acc[a][b] = (f32x4){0.f, 0.f, 0.f, 0.f};

        #pragma unroll
        for (int kt = 0; kt < 4; kt++) {
            #pragma unroll
            for (int nj = 0; nj < 5; nj++) {
                const bf16x8 bb = *(const bf16x8*)(smem + L_H1 + (kt * NT + nj) * 1024 + lane * 16);
                acc[0][nj] = __builtin_amdgcn_mfma_f32_16x16x32_bf16(a8[kt * 2 + 0], bb, acc[0][nj], 0, 0, 0);
                acc[1][nj] = __builtin_amdgcn_mfma_f32_16x16x32_bf16(a8[kt * 2 + 1], bb, acc[1][nj], 0, 0, 0);
            }
        }
        // epilogue: + b2 -> CAT B-frags
        #pragma unroll
        for (int mi = 0; mi < 2; mi++) {
            const int mt = wid * 2 + mi, chb = mt * 16 + lg * 4;
            const float4 bv = *(const float4*)(b2 + chb);
            const int kt = chb >> 5, koff = chb & 31;
            const int lane16 = l15 + 16 * (koff >> 3);
            #pragma unroll
            for (int nj = 0; nj < 5; nj++) {
                const f32x4 v = acc[mi][nj];
                uint2 pk;
                pk.x = cvtpk(v[0] + bv.x, v[1] + bv.y);
                pk.y = cvtpk(v[2] + bv.z, v[3] + bv.w);
                *(uint2*)(smem + L_CAT + (kt * NT + nj) * 1024 + lane16 * 16 + (koff & 7) * 2) = pk;
            }
        }
    }
    __syncthreads();

    // pooled-GEMM A-frags (W3 kt 8..15): issue loads NOW, hide under P3
    bf16x8 ap8[16];
    #pragma unroll
    for (int mi = 0; mi < 2; mi++) {
        const int mt = wid * 2 + mi;
        #pragma unroll
        for (int kk = 0; kk < 8; kk++) {
            const int kt = 8 + kk;
            const int fid = ((mt >> 2) * 4 + (kt >> 2)) * 16 + (mt & 3) * 4 + (kt & 3);
            ap8[mi * 8 + kk] = *(const bf16x8*)(wsb + WS_W3 + (size_t)fid * 1024 + lane * 16);
        }
    }

    // ---------- P3: pooled = max_p h, written directly as B-frags --------
    if (tid < 128) {
        const int pl = tid >> 5, grp = tid & 31;
        const int fragbase = (grp >> 2) * NT;
        const int off16 = 16 * (grp & 3);
        float mx[8];
        #pragma unroll
        for (int e = 0; e < 8; e++) mx[e] = -3.0e38f;
        #pragma unroll 4
        for (int p = 0; p < 20; p++) {
            int pp = p + grp;                 // rotate start to spread banks
            pp -= (pp >= 40) ? 40 : ((pp >= 20) ? 20 : 0);
            const int c = pl * 20 + pp;
            const uint4 v = *(const uint4*)(smem + L_CAT +
                (fragbase + (c >> 4)) * 1024 + ((c & 15) + off16) * 16);
            mx[0] = fmaxf(mx[0], bflo(v.x)); mx[1] = fmaxf(mx[1], bfhi(v.x));
            mx[2] = fmaxf(mx[2], bflo(v.y)); mx[3] = fmaxf(mx[3], bfhi(v.y));
            mx[4] = fmaxf(mx[4], bflo(v.z)); mx[5] = fmaxf(mx[5], bfhi(v.z));
            mx[6] = fmaxf(mx[6], bflo(v.w)); mx[7] = fmaxf(mx[7], bfhi(v.w));
        }
        uint4 pk;
        pk.x = cvtpk(mx[0], mx[1]); pk.y = cvtpk(mx[2], mx[3]);
        pk.z = cvtpk(mx[4], mx[5]); pk.w = cvtpk(mx[6], mx[7]);
        // B-frag: frag kt=grp>>2, slot = pl + 16*(grp&3)
        *(uint4*)(smem + L_PFRAG + (grp >> 2) * 1024 + (pl + 16 * (grp & 3)) * 16) = pk;
    }
    __syncthreads();

    // ---------- pooled GEMM: ap = pooled @ W3[256:]; APOF = ap*sc + OF ----
    {
        f32x4 accp0 = {0.f, 0.f, 0.f, 0.f}, accp1 = {0.f, 0.f, 0.f, 0.f};
        #pragma unroll
        for (int kk = 0; kk < 8; kk++) {
            const bf16x8 bb = *(const bf16x8*)(smem + L_PFRAG + kk * 1024 + lane * 16);
            accp0 = __builtin_amdgcn_mfma_f32_16x16x32_bf16(ap8[kk],     bb, accp0, 0, 0, 0);
            accp1 = __builtin_amdgcn_mfma_f32_16x16x32_bf16(ap8[8 + kk], bb, accp1, 0, 0, 0);
        }
        if (l15 < 4) {
            #pragma unroll
            for (int mi = 0; mi < 2; mi++) {
                const f32x4 v = mi ? accp1 : accp0;
                const int ch0 = (wid * 2 + mi) * 16 + lg * 4;
                const float4 scv = *(const float4*)(smem + L_SC + ch0 * 4);
                const float4 ofv = *(const float4*)(smem + L_OF + ch0 * 4);
                float4 o;
                o.x = fmaf(v[0], scv.x, ofv.x); o.y = fmaf(v[1], scv.y, ofv.y);
                o.z = fmaf(v[2], scv.z, ofv.z); o.w = fmaf(v[3], scv.w, ofv.w);
                *(float4*)(smem + L_APOF + l15 * 1024 + ch0 * 4) = o;
            }
        }
    }
    __syncthreads();

    // APOF per-nj lane bases (poly = col/20)
    unsigned abase[5];
    #pragma unroll
    for (int nj = 0; nj < 5; nj++)
        abase[5 > nj ? nj : 0] = L_APOF + (unsigned)((nj * 16 + l15) / 20) * 1024;

    // ---------- P4: 2 chunks of 128 out-ch: S4 (K=256) fused w/ S5 --------
    f32x4 acc5[5][2];
    #pragma unroll
    for (int a = 0; a < 5; a++) {
        acc5[a][0] = (f32x4){0.f, 0.f, 0.f, 0.f};
        acc5[a][1] = (f32x4){0.f, 0.f, 0.f, 0.f};
    }

    #pragma unroll 1
    for (int chunk = 0; chunk < 2; chunk++) {
        const int mtg = chunk * 8 + wid;
        // prefetch all 8 W3 A-frags (kt 0..7) for this chunk
        bf16x8 a4[8];
        #pragma unroll
        for (int kk = 0; kk < 8; kk++) {
            const int fid = ((mtg >> 2) * 4 + (kk >> 2)) * 16 + (mtg & 3) * 4 + (kk & 3);
            a4[kk] = *(const bf16x8*)(wsb + WS_W3 + (size_t)fid * 1024 + lane * 16);
        }
        f32x4 acc4[5];
        #pragma unroll
        for (int s = 0; s < 5; s++) acc4[s] = (f32x4){0.f, 0.f, 0.f, 0.f};

        #pragma unroll
        for (int ktg = 0; ktg < 8; ktg++) {
            #pragma unroll
            for (int nj = 0; nj < 5; nj++) {
                const bf16x8 bb = *(const bf16x8*)(smem + L_CAT + (ktg * NT + nj) * 1024 + lane * 16);
                acc4[nj] = __builtin_amdgcn_mfma_f32_16x16x32_bf16(a4[ktg], bb, acc4[nj], 0, 0, 0);
            }
        }
        // issue S5 B-frags (W4) now; latency hides under epilogue+barrier
        bf16x8 b5[8];
        #pragma unroll
        for (int kt2 = 0; kt2 < 4; kt2++) {
            #pragma unroll
            for (int njb = 0; njb < 2; njb++) {
                const int ktB = chunk * 4 + kt2, ntB = wid * 2 + njb;
                const int fid = (ktB >> 1) * 32 + ((ntB >> 3) & 1) * 16 + (ntB & 7) * 2 + (ktB & 1);
                b5[kt2 * 2 + njb] = *(const bf16x8*)(wsb + WS_W4 + (size_t)fid * 1024 + lane * 16);
            }
        }
        // epilogue: h2 = relu(acc*sc + APOF) -> h2c A-frags
        {
            const int choff = wid * 16 + lg * 4;
            const int ch0 = mtg * 16 + lg * 4;
            const float4 scv = *(const float4*)(smem + L_SC + ch0 * 4);
            const int kt2 = choff >> 5;
            const int lane16 = l15 + 16 * ((choff & 31) >> 3);
            const int sub = (lg & 1) * 8;
            #pragma unroll
            for (int nj = 0; nj < 5; nj++) {
                const float4 ofv = *(const float4*)(smem + abase[nj] + ch0 * 4);
                const f32x4 v = acc4[nj];
                uint2 pk;
                pk.x = cvtpk(fmaxf(fmaf(v[0], scv.x, ofv.x), 0.f),
                             fmaxf(fmaf(v[1], scv.y, ofv.y), 0.f));
                pk.y = cvtpk(fmaxf(fmaf(v[2], scv.z, ofv.z), 0.f),
                             fmaxf(fmaf(v[3], scv.w, ofv.w), 0.f));
                *(uint2*)(smem + L_H2C + (nj * 4 + kt2) * 1024 + lane16 * 16 + sub) = pk;
            }
        }
        __syncthreads();

        // S5: acc5 += h2c @ W4[chunk]
        #pragma unroll
        for (int kt2 = 0; kt2 < 4; kt2++) {
            #pragma unroll
            for (int mi = 0; mi < 5; mi++) {
                const bf16x8 a = *(const bf16x8*)(smem + L_H2C + (mi * 4 + kt2) * 1024 + lane * 16);
                acc5[mi][0] = __builtin_amdgcn_mfma_f32_16x16x32_bf16(a, b5[kt2 * 2 + 0], acc5[mi][0], 0, 0, 0);
                acc5[mi][1] = __builtin_amdgcn_mfma_f32_16x16x32_bf16(a, b5[kt2 * 2 + 1], acc5[mi][1], 0, 0, 0);
            }
        }
        __syncthreads();
    }

    // ---------- P5: 4-col run maxes -> CAT overlay ----------
    #pragma unroll
    for (int mi = 0; mi < 5; mi++) {
        const int run = mi * 4 + lg;
        #pragma unroll
        for (int njb = 0; njb < 2; njb++) {
            const int ch = (wid * 2 + njb) * 16 + l15;
            const f32x4 v = acc5[mi][njb];
            const float m4 = fmaxf(fmaxf(v[0], v[1]), fmaxf(v[2], v[3]));
            *(unsigned short*)(smem + L_CAT + run * 512 + ch * 2) = f2bf(m4);
        }
    }
    __syncthreads();

    // ---------- P6: final max + b4 + type_emb ----------
    #pragma unroll
    for (int i = 0; i < 2; i++) {
        const int idx = i * 512 + tid, pl = idx >> 8, ch = idx & 255;
        if (bbase + pl < nact) {
            const int gpoly = list[bbase + pl];
            float mx = -3.0e38f;
            #pragma unroll
            for (int j = 0; j < 5; j++)
                mx = fmaxf(mx, bf2f(*(const unsigned short*)(smem + L_CAT +
                        (pl * 5 + j) * 512 + ch * 2)));
            out0[(size_t)gpoly * 256 + ch] = mx + b4[ch] + temb[label[gpoly] * 256 + ch];
        }
    }
}

// ---------------------------------------------------------------------------
// PE: 32 rows/block x 512 blocks (2 blocks/CU). Deep prefetch.
// ---------------------------------------------------------------------------
#define PR     32
#define P_SINE 0          // 16 frags (kt0..7 x nt0..1)  16384
#define P_PHC  16384      // 32 frags (mt0..1 x kt0..15) 32768

__global__ __launch_bounds__(512, 4) void pe_mfma(
    const float* __restrict__ tgt, const float* __restrict__ out2,
    const float* __restrict__ bp1, const float* __restrict__ bp2,
    const float* __restrict__ pcr, const char* __restrict__ wsb,
    float* __restrict__ out1)
{
    __shared__ __align__(16) char sm[49152];
    const int tid  = threadIdx.x;
    const int wid  = tid >> 6;
    const int lane = tid & 63;
    const int l15  = lane & 15, lg = lane >> 4;
    const int base = blockIdx.x * PR;

    const float lox = pcr[0], loy = pcr[1];
    const float sx = 1.0f / (pcr[3] - pcr[0]), sy = 1.0f / (pcr[4] - pcr[1]);

    // sine B-frags: 1024 slots, 2 per thread
    #pragma unroll
    for (int i = 0; i < 2; i++) {
        const int u = i * 512 + tid;
        const int kt = u >> 7, nt = (u >> 6) & 1, s = u & 63;
        const int row = nt * 16 + (s & 15);
        const int lgs = s >> 4;
        const size_t gp = (size_t)(base + row) * 42;
        const float posx = (tgt[gp + 20] - lox) * sx;
        const float posy = (tgt[gp + 21] - loy) * sy;
        float fv[8];
        #pragma unroll
        for (int e = 0; e < 8; e++) {
            const int ch = kt * 32 + lgs * 8 + e;
            const float pos = (ch < 128) ? posy : posx;
            const int j7 = ch & 127, fi = j7 >> 1;
            const float freq = exp2f(-(float)fi * 0.20762050593046f) * 6.283185307179586f;
            const float arg = pos * freq;
            fv[e] = (j7 & 1) ? __cosf(arg) : __sinf(arg);
        }
        uint4 pk;
        pk.x = cvtpk(fv[0], fv[1]); pk.y = cvtpk(fv[2], fv[3]);
        pk.z = cvtpk(fv[4], fv[5]); pk.w = cvtpk(fv[6], fv[7]);
        *(uint4*)(sm + P_SINE + (kt * 2 + nt) * 1024 + s * 16) = pk;
    }
    __syncthreads();

    const int mw = wid >> 1, nw = wid & 1;

    f32x4 acc5[2][2];
    acc5[0][0] = (f32x4){0.f,0.f,0.f,0.f}; acc5[0][1] = (f32x4){0.f,0.f,0.f,0.f};
    acc5[1][0] = (f32x4){0.f,0.f,0.f,0.f}; acc5[1][1] = (f32x4){0.f,0.f,0.f,0.f};

    #pragma unroll 1
    for (int chunk = 0; chunk < 8; chunk++) {
        const int mt1 = chunk * 4 + mw;
        // prefetch all 8 Wp1 A-frags
        bf16x8 a8[8];
        #pragma unroll
        for (int kk = 0; kk < 8; kk++) {
            const int fid = ((mt1 >> 2) * 2 + (kk >> 2)) * 16 + (mt1 & 3) * 4 + (kk & 3);
            a8[kk] = *(const bf16x8*)(wsb + WS_WP1 + (size_t)fid * 1024 + lane * 16);
        }
        f32x4 acc4 = {0.f, 0.f, 0.f, 0.f};
        #pragma unroll
        for (int kk = 0; kk < 8; kk++) {
            const bf16x8 bb = *(const bf16x8*)(sm + P_SINE + (kk * 2 + nw) * 1024 + lane * 16);
            acc4 = __builtin_amdgcn_mfma_f32_16x16x32_bf16(a8[kk], bb, acc4, 0, 0, 0);
        }
        // issue GEMM2 B-frags (Wp2) for this chunk
        bf16x8 b5[4];
        #pragma unroll
        for (int kj = 0; kj < 2; kj++) {
            #pragma unroll
            for (int njj = 0; njj < 2; njj++) {
                const int ktB = chunk * 2 + kj, ntB = wid * 2 + njj;
                const int fid = (ktB >> 1) * 32 + ((ntB >> 3) & 1) * 16 + (ntB & 7) * 2 + (ktB & 1);
                b5[kj * 2 + njj] = *(const bf16x8*)(wsb + WS_WP2 + (size_t)fid * 1024 + lane * 16);
            }
        }
        // epilogue: + bp1, relu -> PHC A-frags
        {
            const int ch0 = mt1 * 16 + lg * 4;
            const float4 bv = *(const float4*)(bp1 + ch0);
            const int ktA = mt1 >> 1;
            const int slot = l15 + 16 * ((mt1 & 1) * 2 + (lg >> 1));
            uint2 pk;
            pk.x = cvtpk(fmaxf(acc4[0] + bv.x, 0.f), fmaxf(acc4[1] + bv.y, 0.f));
            pk.y = cvtpk(fmaxf(acc4[2] + bv.z, 0.f), fmaxf(acc4[3] + bv.w, 0.f));
            *(uint2*)(sm + P_PHC + (nw * 16 + ktA) * 1024 + slot * 16 + (lg & 1) * 8) = pk;
        }
        __syncthreads();
        // GEMM2: acc5 += phc @ Wp2[chunk]
        #pragma unroll
        for (int kj = 0; kj < 2; kj++) {
            bf16x8 a[2];
            a[0] = *(const bf16x8*)(sm + P_PHC + (0 * 16 + chunk * 2 + kj) * 1024 + lane * 16);
            a[1] = *(const bf16x8*)(sm + P_PHC + (1 * 16 + chunk * 2 + kj) * 1024 + lane * 16);
            #pragma unroll
            for (int njj = 0; njj < 2; njj++) {
                acc5[0][njj] = __builtin_amdgcn_mfma_f32_16x16x32_bf16(a[0], b5[kj * 2 + njj], acc5[0][njj], 0, 0, 0);
                acc5[1][njj] = __builtin_amdgcn_mfma_f32_16x16x32_bf16(a[1], b5[kj * 2 + njj], acc5[1][njj], 0, 0, 0);
            }
        }
        __syncthreads();
    }

    // final: +bp2, masked
    #pragma unroll
    for (int mi = 0; mi < 2; mi++) {
        #pragma unroll
        for (int njj = 0; njj < 2; njj++) {
            const int ch = (wid * 2 + njj) * 16 + l15;
            const float bo = bp2[ch];
            const f32x4 v = acc5[mi][njj];
            #pragma unroll
            for (int r = 0; r < 4; r++) {
                const int row = base + mi * 16 + lg * 4 + r;
                out1[(size_t)row * 256 + ch] = (out2[row] == 0.0f) ? (v[r] + bo) : 0.f;
            }
        }
    }
}

extern "C" void kernel_launch(void* const* d_in, const int* in_sizes, int n_in,
                              void* d_out, int out_size, void* d_ws, size_t ws_size,
                              hipStream_t stream) {
    const float*         tgt   = (const float*)d_in[0];
    const int*           lab   = (const int*)d_in[1];
    const unsigned char* mraw  = (const unsigned char*)d_in[2];
    const float* W1  = (const float*)d_in[3];
    const float* b1  = (const float*)d_in[4];
    const float* g1  = (const float*)d_in[5];
    const float* be1 = (const float*)d_in[6];
    const float* m1  = (const float*)d_in[7];
    const float* v1  = (const float*)d_in[8];
    const float* W2  = (const float*)d_in[9];
    const float* b2  = (const float*)d_in[10];
    const float* W3  = (const float*)d_in[11];
    const float* b3  = (const float*)d_in[12];
    const float* g2  = (const float*)d_in[13];
    const float* be2 = (const float*)d_in[14];
    const float* m2  = (const float*)d_in[15];
    const float* v2  = (const float*)d_in[16];
    const float* W4  = (const float*)d_in[17];
    const float* b4  = (const float*)d_in[18];
    const float* temb = (const float*)d_in[19];
    const float* Wp1 = (const float*)d_in[20];
    const float* bp1 = (const float*)d_in[21];
    const float* Wp2 = (const float*)d_in[22];
    const float* bp2 = (const float*)d_in[23];
    const float* pcr = (const float*)d_in[24];

    float* out0 = (float*)d_out;
    float* out1 = out0 + (size_t)NPOLY * 256;
    float* out2 = out1 + (size_t)NPOLY * 256;

    char*           wsb  = (char*)d_ws;
    int*            cnt  = (int*)(wsb + WS_CNT);
    unsigned short* list = (unsigned short*)(wsb + WS_LIST);
    unsigned short* wsu  = (unsigned short*)d_ws;

    hipFuncSetAttribute(reinterpret_cast<const void*>(enc_mfma),
                        hipFuncAttributeMaxDynamicSharedMemorySize, L_TOT);

    hipMemsetAsync(cnt, 0, 4, stream);
    norm_mask<<<NPOLY / 256, 256, 0, stream>>>(mraw, out2, list, cnt, out0);
    prep_weights<<<960, 512, 0, stream>>>(W2, W3, W4, Wp1, Wp2, wsu);
    enc_mfma<<<NPOLY / NPB, 512, L_TOT, stream>>>(
        tgt, lab, list, cnt, W1, b1, g1, be1, m1, v1, b2, b3, g2, be2, m2, v2,
        b4, temb, wsb, out0);
    pe_mfma<<<NPOLY / PR, 512, 0, stream>>>(tgt, out2, bp1, bp2, pcr, wsb, out1);
}